// Round 4
// baseline (2636.330 us; speedup 1.0000x reference)
//
#include <hip/hip_runtime.h>
#include <stdint.h>

#define NN 10000
#define NE 160000

// ---------- bf16 helpers (internal staging format; I/O is f32) ----------
__device__ __forceinline__ float bf2f(unsigned short u) {
    return __uint_as_float(((uint32_t)u) << 16);
}
__device__ __forceinline__ float bflo(uint32_t u) { return __uint_as_float(u << 16); }
__device__ __forceinline__ float bfhi(uint32_t u) { return __uint_as_float(u & 0xffff0000u); }
__device__ __forceinline__ unsigned short f2bf(float f) {
    uint32_t u = __float_as_uint(f);
    u += 0x7fffu + ((u >> 16) & 1u);   // RNE
    return (unsigned short)(u >> 16);
}
__device__ __forceinline__ uint32_t pack2(float lo, float hi) {
    return (uint32_t)f2bf(lo) | ((uint32_t)f2bf(hi) << 16);
}
__device__ __forceinline__ float silu2(float x) {
    return 1.679177f * x / (1.f + __expf(-x));
}

// ---------------------------------------------------------------------------
// K1: up-projection.  xw[n] layout: [y0 (128) | y1 m-major: 128 + m*128 + v]
// 16 nodes/block (grid 625). thread: j=t&3 node-in-quad, g=t>>2 col-group of 8.
// Weights staged f32->bf16 in LDS (64 KB total).
// ---------------------------------------------------------------------------
__global__ __launch_bounds__(256) void k_up(const float* __restrict__ nf,
                                            const float* __restrict__ Wu0,
                                            const float* __restrict__ Wu1,
                                            float* __restrict__ xw) {
    __shared__ __align__(16) unsigned short w0s[128 * 128];
    __shared__ __align__(16) unsigned short w1s[128 * 128];
    int t = threadIdx.x;
    {
        const float4* g0 = (const float4*)Wu0;
        const float4* g1 = (const float4*)Wu1;
        uint2* s0 = (uint2*)w0s;
        uint2* s1 = (uint2*)w1s;
        for (int i = t; i < 4096; i += 256) {
            float4 a = g0[i], b = g1[i];
            s0[i] = make_uint2(pack2(a.x, a.y), pack2(a.z, a.w));
            s1[i] = make_uint2(pack2(b.x, b.y), pack2(b.z, b.w));
        }
    }
    __syncthreads();
    int j = t & 3, g = t >> 2;           // g in [0,64): wave-uniform type
    bool ty0 = g < 16;
    int m = 0, v0;
    if (ty0) v0 = g << 3;
    else { int gg = g - 16; m = gg >> 4; v0 = (gg & 15) << 3; }
    const unsigned short* wbase = (ty0 ? w0s : w1s) + v0;
    int col = ty0 ? v0 : (128 + (m << 7) + v0);
    const float s = 0.08838834764831845f;   // 1/sqrt(128)

    for (int nq = 0; nq < 4; ++nq) {
        int n = blockIdx.x * 16 + nq * 4 + j;
        const float* xrow = nf + (size_t)n * 512;
        float acc[8] = {0, 0, 0, 0, 0, 0, 0, 0};
#pragma unroll 4
        for (int u = 0; u < 128; ++u) {
            uint4 wv = *(const uint4*)(wbase + u * 128);
            float xv = ty0 ? xrow[u] : xrow[128 + u * 3 + m];
            acc[0] += xv * bflo(wv.x); acc[1] += xv * bfhi(wv.x);
            acc[2] += xv * bflo(wv.y); acc[3] += xv * bfhi(wv.y);
            acc[4] += xv * bflo(wv.z); acc[5] += xv * bfhi(wv.z);
            acc[6] += xv * bflo(wv.w); acc[7] += xv * bfhi(wv.w);
        }
        float* o = xw + (size_t)n * 512 + col;
#pragma unroll
        for (int q = 0; q < 8; ++q) o[q] = acc[q] * s;
    }
}

// ---------------------------------------------------------------------------
// K2: edge MLP stages 1-3 -> h3 (NE x 64, bf16). one edge per thread.
// Weights transposed f32 in LDS, read as float4 broadcasts (4x fewer LDS instr).
// ---------------------------------------------------------------------------
__global__ __launch_bounds__(256) void k_mlp_a(const float* __restrict__ ef,
                                               const float* __restrict__ W1,
                                               const float* __restrict__ W2,
                                               const float* __restrict__ W3,
                                               unsigned short* __restrict__ h3w) {
    __shared__ float w1t[64 * 8];    // [j][k]
    __shared__ float w2t[64 * 64];   // [j][k]
    __shared__ float w3t[64 * 64];
    int t = threadIdx.x;
    for (int i = t; i < 8 * 64; i += 256) {
        int k = i >> 6, jj = i & 63;
        w1t[jj * 8 + k] = W1[i];
    }
    for (int i = t; i < 64 * 64; i += 256) {
        int k = i >> 6, jj = i & 63;
        w2t[jj * 64 + k] = W2[i];
        w3t[jj * 64 + k] = W3[i];
    }
    __syncthreads();
    int e = blockIdx.x * 256 + t;
    const float4* ep = (const float4*)(ef + (size_t)e * 8);
    float4 ea4 = ep[0], eb4 = ep[1];
    float h0[8] = {ea4.x, ea4.y, ea4.z, ea4.w, eb4.x, eb4.y, eb4.z, eb4.w};
    const float sc1 = 0.3535533905932738f;  // 1/sqrt(8)
#pragma unroll
    for (int k = 0; k < 8; ++k) h0[k] *= sc1;

    float ha[64], hb[64];
    for (int jj = 0; jj < 64; ++jj) {
        const float4* wr = (const float4*)(w1t + jj * 8);
        float4 wa = wr[0], wb = wr[1];
        float s = h0[0] * wa.x + h0[1] * wa.y + h0[2] * wa.z + h0[3] * wa.w
                + h0[4] * wb.x + h0[5] * wb.y + h0[6] * wb.z + h0[7] * wb.w;
        ha[jj] = silu2(s);
    }
    for (int jj = 0; jj < 64; ++jj) {
        const float4* wr = (const float4*)(w2t + jj * 64);
        float s = 0.f;
#pragma unroll
        for (int q = 0; q < 16; ++q) {
            float4 w = wr[q];
            s += ha[q * 4 + 0] * w.x + ha[q * 4 + 1] * w.y
               + ha[q * 4 + 2] * w.z + ha[q * 4 + 3] * w.w;
        }
        hb[jj] = silu2(s * 0.125f);
    }
    for (int jj = 0; jj < 64; ++jj) {
        const float4* wr = (const float4*)(w3t + jj * 64);
        float s = 0.f;
#pragma unroll
        for (int q = 0; q < 16; ++q) {
            float4 w = wr[q];
            s += hb[q * 4 + 0] * w.x + hb[q * 4 + 1] * w.y
               + hb[q * 4 + 2] * w.z + hb[q * 4 + 3] * w.w;
        }
        ha[jj] = silu2(s * 0.125f);
    }
    uint4* orow = (uint4*)(h3w + (size_t)e * 64);
#pragma unroll
    for (int q = 0; q < 8; ++q) {
        uint4 v;
        v.x = pack2(ha[q * 8 + 0], ha[q * 8 + 1]);
        v.y = pack2(ha[q * 8 + 2], ha[q * 8 + 3]);
        v.z = pack2(ha[q * 8 + 4], ha[q * 8 + 5]);
        v.w = pack2(ha[q * 8 + 6], ha[q * 8 + 7]);
        orow[q] = v;
    }
}

// ---------------------------------------------------------------------------
// K3: CSR build by receiver (zero -> histogram -> scan -> fill)
// ---------------------------------------------------------------------------
__global__ void k_zero(int* __restrict__ p, int n) {
    int i = blockIdx.x * 256 + threadIdx.x;
    if (i < n) p[i] = 0;
}
__global__ void k_hist(const int* __restrict__ ei, int* __restrict__ counts) {
    int e = blockIdx.x * 256 + threadIdx.x;
    if (e < NE) atomicAdd(&counts[ei[NE + e]], 1);
}
__global__ __launch_bounds__(1024) void k_scan(const int* __restrict__ counts,
                                               int* __restrict__ offs,
                                               int* __restrict__ cursor) {
    __shared__ int sums[1024];
    int t = threadIdx.x;
    int base = t * 10;
    int s = 0;
    for (int i = 0; i < 10; ++i) {
        int idx = base + i;
        if (idx < NN) s += counts[idx];
    }
    sums[t] = s;
    __syncthreads();
    for (int d = 1; d < 1024; d <<= 1) {
        int v = (t >= d) ? sums[t - d] : 0;
        __syncthreads();
        if (t >= d) sums[t] += v;
        __syncthreads();
    }
    int run = (t == 0) ? 0 : sums[t - 1];
    for (int i = 0; i < 10; ++i) {
        int idx = base + i;
        if (idx < NN) {
            offs[idx] = run;
            cursor[idx] = run;
            run += counts[idx];
        }
    }
    if (t == 0) offs[NN] = NE;
}
__global__ void k_fill(const int* __restrict__ ei, int* __restrict__ cursor,
                       int* __restrict__ elist) {
    int e = blockIdx.x * 256 + threadIdx.x;
    if (e < NE) {
        int slot = atomicAdd(&cursor[ei[NE + e]], 1);
        elist[slot] = e;
    }
}

// ---------------------------------------------------------------------------
// K4: fused W4-projection + message reduction.
// One WAVE per receiver node (4 nodes/iter, 4 iters -> 16 nodes/block, grid 625).
// Lane owns 8 contiguous W4 cols (colb = lane*8): per k one ds_read_b128
// (contiguous 16B/lane, conflict-free). j = lane>>4 selects w1/w2/w3/w4 block.
// msg[n] layout (bf16): [m0 (256) | m1 m-major: 256 + m*256 + c]
// ---------------------------------------------------------------------------
__global__ __launch_bounds__(256) void k_msg(const float* __restrict__ xw,
                                             const unsigned short* __restrict__ h3w,
                                             const float* __restrict__ W4,
                                             const float* __restrict__ ea,
                                             const int* __restrict__ ei,
                                             const int* __restrict__ offs,
                                             const int* __restrict__ elist,
                                             unsigned short* __restrict__ msgb) {
    __shared__ __align__(16) unsigned short w4s[64 * 512];   // [k][col] bf16, 64 KB
    int t = threadIdx.x;
    {
        const float4* g = (const float4*)W4;
        uint2* s2 = (uint2*)w4s;
        for (int i = t; i < 8192; i += 256) {
            float4 v = g[i];
            s2[i] = make_uint2(pack2(v.x, v.y), pack2(v.z, v.w));
        }
    }
    __syncthreads();
    int wave = t >> 6, lane = t & 63;
    int j = lane >> 4;              // 0:w1 1:w2 2:w3 3:w4
    int cl = (lane & 15) * 8;       // local col within 128-block
    int colb = lane * 8;            // global W4 col
    const unsigned short* wbase = w4s + colb;

    for (int nq = 0; nq < 4; ++nq) {
        int n = blockIdx.x * 16 + nq * 4 + wave;
        int beg = offs[n], end = offs[n + 1];
        float A[24];
#pragma unroll
        for (int q = 0; q < 24; ++q) A[q] = 0.f;

        for (int i = beg; i < end; ++i) {
            int e = elist[i];           // wave-uniform
            int snd = ei[e];
            float4 eav = *(const float4*)(ea + (size_t)e * 4);
            float y0 = eav.x, y1x = eav.y, y1y = eav.z, y1z = eav.w;
            const uint4* hr = (const uint4*)(h3w + (size_t)e * 64);

            float d[8] = {0, 0, 0, 0, 0, 0, 0, 0};
#pragma unroll
            for (int q = 0; q < 8; ++q) {
                uint4 hq = hr[q];
                float hk[8];
                hk[0] = bflo(hq.x); hk[1] = bfhi(hq.x);
                hk[2] = bflo(hq.y); hk[3] = bfhi(hq.y);
                hk[4] = bflo(hq.z); hk[5] = bfhi(hq.z);
                hk[6] = bflo(hq.w); hk[7] = bfhi(hq.w);
#pragma unroll
                for (int s = 0; s < 8; ++s) {
                    uint4 wv = *(const uint4*)(wbase + (q * 8 + s) * 512);
                    float h = hk[s];
                    d[0] += h * bflo(wv.x); d[1] += h * bfhi(wv.x);
                    d[2] += h * bflo(wv.y); d[3] += h * bfhi(wv.y);
                    d[4] += h * bflo(wv.z); d[5] += h * bfhi(wv.z);
                    d[6] += h * bflo(wv.w); d[7] += h * bfhi(wv.w);
                }
            }
#pragma unroll
            for (int q = 0; q < 8; ++q) d[q] *= 0.125f;   // 1/sqrt(64)

            const float* xr = xw + (size_t)snd * 512;
            if (j == 0) {                 // p1[c] = w1*s0*y0 -> m0[c]
                float4 sa = *(const float4*)(xr + cl);
                float4 sb = *(const float4*)(xr + cl + 4);
                A[0] += d[0] * sa.x * y0; A[1] += d[1] * sa.y * y0;
                A[2] += d[2] * sa.z * y0; A[3] += d[3] * sa.w * y0;
                A[4] += d[4] * sb.x * y0; A[5] += d[5] * sb.y * y0;
                A[6] += d[6] * sb.z * y0; A[7] += d[7] * sb.w * y0;
            } else if (j == 1) {          // p2[c][m] = w2*s0*y1[m] -> m1 rows c
                float4 sa = *(const float4*)(xr + cl);
                float4 sb = *(const float4*)(xr + cl + 4);
                float s0v[8] = {sa.x, sa.y, sa.z, sa.w, sb.x, sb.y, sb.z, sb.w};
#pragma unroll
                for (int q = 0; q < 8; ++q) {
                    float tv = d[q] * s0v[q];
                    A[q]      += tv * y1x;
                    A[8 + q]  += tv * y1y;
                    A[16 + q] += tv * y1z;
                }
            } else if (j == 2) {          // p3[c][m] = w3*s1[c][m]*y0 -> m1 rows 128+c
#pragma unroll
                for (int m = 0; m < 3; ++m) {
                    float4 sa = *(const float4*)(xr + 128 + m * 128 + cl);
                    float4 sb = *(const float4*)(xr + 128 + m * 128 + cl + 4);
                    float s1v[8] = {sa.x, sa.y, sa.z, sa.w, sb.x, sb.y, sb.z, sb.w};
#pragma unroll
                    for (int q = 0; q < 8; ++q)
                        A[m * 8 + q] += d[q] * s1v[q] * y0;
                }
            } else {                      // p4[c] = w4*(s1.y1)/sqrt3 -> m0[128+c]
                float4 xa = *(const float4*)(xr + 128 + cl);
                float4 xb = *(const float4*)(xr + 128 + cl + 4);
                float4 ya = *(const float4*)(xr + 256 + cl);
                float4 yb = *(const float4*)(xr + 256 + cl + 4);
                float4 za = *(const float4*)(xr + 384 + cl);
                float4 zb = *(const float4*)(xr + 384 + cl + 4);
                float sx[8] = {xa.x, xa.y, xa.z, xa.w, xb.x, xb.y, xb.z, xb.w};
                float sy[8] = {ya.x, ya.y, ya.z, ya.w, yb.x, yb.y, yb.z, yb.w};
                float sz[8] = {za.x, za.y, za.z, za.w, zb.x, zb.y, zb.z, zb.w};
#pragma unroll
                for (int q = 0; q < 8; ++q) {
                    float dt = sx[q] * y1x + sy[q] * y1y + sz[q] * y1z;
                    A[q] += d[q] * dt * 0.5773502691896258f;
                }
            }
        }

        unsigned short* mr = msgb + (size_t)n * 1024;
        if (j == 0) {
            uint4 v = {pack2(A[0], A[1]), pack2(A[2], A[3]),
                       pack2(A[4], A[5]), pack2(A[6], A[7])};
            *(uint4*)(mr + cl) = v;
        } else if (j == 1) {
#pragma unroll
            for (int m = 0; m < 3; ++m) {
                uint4 v = {pack2(A[m*8+0], A[m*8+1]), pack2(A[m*8+2], A[m*8+3]),
                           pack2(A[m*8+4], A[m*8+5]), pack2(A[m*8+6], A[m*8+7])};
                *(uint4*)(mr + 256 + m * 256 + cl) = v;
            }
        } else if (j == 2) {
#pragma unroll
            for (int m = 0; m < 3; ++m) {
                uint4 v = {pack2(A[m*8+0], A[m*8+1]), pack2(A[m*8+2], A[m*8+3]),
                           pack2(A[m*8+4], A[m*8+5]), pack2(A[m*8+6], A[m*8+7])};
                *(uint4*)(mr + 256 + m * 256 + 128 + cl) = v;
            }
        } else {
            uint4 v = {pack2(A[0], A[1]), pack2(A[2], A[3]),
                       pack2(A[4], A[5]), pack2(A[6], A[7])};
            *(uint4*)(mr + 128 + cl) = v;
        }
    }
}

// ---------------------------------------------------------------------------
// K5a: o0 = msg0 @ W_out0 /16/10 -> out cols [0,128)
// K5b: o1[v][m] = sum_u msg1[u][m] W_out1[u][v] /16/10 -> out col 128+v*3+m
// 32 nodes/block; weights staged f32->bf16 in LDS (64 KB).
// ---------------------------------------------------------------------------
__global__ __launch_bounds__(256) void k_out0(const unsigned short* __restrict__ msgb,
                                              const float* __restrict__ W,
                                              float* __restrict__ out) {
    __shared__ __align__(16) unsigned short wls[256 * 128];
    int t = threadIdx.x;
    {
        const float4* g = (const float4*)W;
        uint2* s2 = (uint2*)wls;
        for (int i = t; i < 8192; i += 256) {
            float4 v = g[i];
            s2[i] = make_uint2(pack2(v.x, v.y), pack2(v.z, v.w));
        }
    }
    __syncthreads();
    int v = t & 127, half = t >> 7;
    for (int jj = 0; jj < 16; ++jj) {
        int n = blockIdx.x * 32 + jj * 2 + half;
        if (n >= NN) break;
        const unsigned short* m0 = msgb + (size_t)n * 1024;
        float acc = 0.f;
#pragma unroll 8
        for (int u = 0; u < 256; ++u) acc += bf2f(m0[u]) * bf2f(wls[u * 128 + v]);
        out[(size_t)n * 512 + v] = acc * 0.00625f;
    }
}
__global__ __launch_bounds__(256) void k_out1(const unsigned short* __restrict__ msgb,
                                              const float* __restrict__ W,
                                              float* __restrict__ out) {
    __shared__ __align__(16) unsigned short wls[256 * 128];
    int t = threadIdx.x;
    {
        const float4* g = (const float4*)W;
        uint2* s2 = (uint2*)wls;
        for (int i = t; i < 8192; i += 256) {
            float4 v = g[i];
            s2[i] = make_uint2(pack2(v.x, v.y), pack2(v.z, v.w));
        }
    }
    __syncthreads();
    int v = t & 127, half = t >> 7;
    for (int jj = 0; jj < 16; ++jj) {
        int n = blockIdx.x * 32 + jj * 2 + half;
        if (n >= NN) break;
        const unsigned short* m1 = msgb + (size_t)n * 1024 + 256;
        float a0 = 0.f, a1 = 0.f, a2 = 0.f;
#pragma unroll 4
        for (int u = 0; u < 256; ++u) {
            float w = bf2f(wls[u * 128 + v]);
            a0 += bf2f(m1[u]) * w;
            a1 += bf2f(m1[256 + u]) * w;
            a2 += bf2f(m1[512 + u]) * w;
        }
        float* o = out + (size_t)n * 512 + 128 + v * 3;
        o[0] = a0 * 0.00625f;
        o[1] = a1 * 0.00625f;
        o[2] = a2 * 0.00625f;
    }
}

// ---------------------------------------------------------------------------
extern "C" void kernel_launch(void* const* d_in, const int* in_sizes, int n_in,
                              void* d_out, int out_size, void* d_ws, size_t ws_size,
                              hipStream_t stream) {
    const float* nf  = (const float*)d_in[0];
    const float* ea  = (const float*)d_in[1];
    const float* ef  = (const float*)d_in[2];
    const int*   ei  = (const int*)d_in[3];
    const float* Wu0 = (const float*)d_in[4];
    const float* Wu1 = (const float*)d_in[5];
    const float* W1  = (const float*)d_in[6];
    const float* W2  = (const float*)d_in[7];
    const float* W3  = (const float*)d_in[8];
    const float* W4  = (const float*)d_in[9];
    const float* Wo0 = (const float*)d_in[10];
    const float* Wo1 = (const float*)d_in[11];
    float* out = (float*)d_out;

    // workspace layout (bytes), total ~62.2 MiB (proven safe in round 3):
    //   [0,          20,480,000)   xw    NN x 512 f32
    //   [20,480,000, 40,960,000)   h3    NE x 64 bf16
    //   [40,960,000, 61,440,000)   msg   NN x 1024 bf16
    //   [61,440,000, ...)          CSR ints
    char* ws = (char*)d_ws;
    float*          xw   = (float*)ws;
    unsigned short* h3w  = (unsigned short*)(ws + 20480000);
    unsigned short* msgb = (unsigned short*)(ws + 40960000);
    int* ib     = (int*)(ws + 61440000);
    int* counts = ib;              // NN
    int* offs   = ib + 10240;      // NN+1
    int* cursor = ib + 20480;      // NN
    int* elist  = ib + 30720;      // NE

    k_up   <<<625, 256, 0, stream>>>(nf, Wu0, Wu1, xw);
    k_mlp_a<<<625, 256, 0, stream>>>(ef, W1, W2, W3, h3w);
    k_zero <<<40, 256, 0, stream>>>(counts, NN);
    k_hist <<<625, 256, 0, stream>>>(ei, counts);
    k_scan <<<1, 1024, 0, stream>>>(counts, offs, cursor);
    k_fill <<<625, 256, 0, stream>>>(ei, cursor, elist);
    k_msg  <<<625, 256, 0, stream>>>(xw, h3w, W4, ea, ei, offs, elist, msgb);
    k_out0 <<<313, 256, 0, stream>>>(msgb, Wo0, out);
    k_out1 <<<313, 256, 0, stream>>>(msgb, Wo1, out);
}

// Round 5
// 824.799 us; speedup vs baseline: 3.1963x; 3.1963x over previous
//
#include <hip/hip_runtime.h>
#include <stdint.h>

#define NN 10000
#define NE 160000

typedef short short8 __attribute__((ext_vector_type(8)));
typedef float f32x4 __attribute__((ext_vector_type(4)));

// ---------- bf16 helpers (internal staging format; I/O is f32) ----------
__device__ __forceinline__ float bf2f(unsigned short u) {
    return __uint_as_float(((uint32_t)u) << 16);
}
__device__ __forceinline__ float bflo(uint32_t u) { return __uint_as_float(u << 16); }
__device__ __forceinline__ float bfhi(uint32_t u) { return __uint_as_float(u & 0xffff0000u); }
__device__ __forceinline__ unsigned short f2bf(float f) {
    uint32_t u = __float_as_uint(f);
    u += 0x7fffu + ((u >> 16) & 1u);   // RNE
    return (unsigned short)(u >> 16);
}
__device__ __forceinline__ uint32_t pack2(float lo, float hi) {
    return (uint32_t)f2bf(lo) | ((uint32_t)f2bf(hi) << 16);
}
__device__ __forceinline__ float silu2(float x) {
    return 1.679177f * x / (1.f + __expf(-x));
}

// ---------------------------------------------------------------------------
// K1: up-projection.  xw[n] layout: [y0 (128) | y1 m-major: 128 + m*128 + v]
// 16 nodes/block (grid 625). Weights staged f32->bf16 in LDS.
// ---------------------------------------------------------------------------
__global__ __launch_bounds__(256) void k_up(const float* __restrict__ nf,
                                            const float* __restrict__ Wu0,
                                            const float* __restrict__ Wu1,
                                            float* __restrict__ xw) {
    __shared__ __align__(16) unsigned short w0s[128 * 128];
    __shared__ __align__(16) unsigned short w1s[128 * 128];
    int t = threadIdx.x;
    {
        const float4* g0 = (const float4*)Wu0;
        const float4* g1 = (const float4*)Wu1;
        uint2* s0 = (uint2*)w0s;
        uint2* s1 = (uint2*)w1s;
        for (int i = t; i < 4096; i += 256) {
            float4 a = g0[i], b = g1[i];
            s0[i] = make_uint2(pack2(a.x, a.y), pack2(a.z, a.w));
            s1[i] = make_uint2(pack2(b.x, b.y), pack2(b.z, b.w));
        }
    }
    __syncthreads();
    int j = t & 3, g = t >> 2;
    bool ty0 = g < 16;
    int m = 0, v0;
    if (ty0) v0 = g << 3;
    else { int gg = g - 16; m = gg >> 4; v0 = (gg & 15) << 3; }
    const unsigned short* wbase = (ty0 ? w0s : w1s) + v0;
    int col = ty0 ? v0 : (128 + (m << 7) + v0);
    const float s = 0.08838834764831845f;   // 1/sqrt(128)

    for (int nq = 0; nq < 4; ++nq) {
        int n = blockIdx.x * 16 + nq * 4 + j;
        const float* xrow = nf + (size_t)n * 512;
        float acc[8] = {0, 0, 0, 0, 0, 0, 0, 0};
#pragma unroll 4
        for (int u = 0; u < 128; ++u) {
            uint4 wv = *(const uint4*)(wbase + u * 128);
            float xv = ty0 ? xrow[u] : xrow[128 + u * 3 + m];
            acc[0] += xv * bflo(wv.x); acc[1] += xv * bfhi(wv.x);
            acc[2] += xv * bflo(wv.y); acc[3] += xv * bfhi(wv.y);
            acc[4] += xv * bflo(wv.z); acc[5] += xv * bfhi(wv.z);
            acc[6] += xv * bflo(wv.w); acc[7] += xv * bfhi(wv.w);
        }
        float* o = xw + (size_t)n * 512 + col;
#pragma unroll
        for (int q = 0; q < 8; ++q) o[q] = acc[q] * s;
    }
}

// ---------------------------------------------------------------------------
// K2: edge MLP stages 1-3 -> h3 (NE x 64, bf16). one edge per thread.
// ---------------------------------------------------------------------------
__global__ __launch_bounds__(256) void k_mlp_a(const float* __restrict__ ef,
                                               const float* __restrict__ W1,
                                               const float* __restrict__ W2,
                                               const float* __restrict__ W3,
                                               unsigned short* __restrict__ h3w) {
    __shared__ float w1t[64 * 8];
    __shared__ float w2t[64 * 64];
    __shared__ float w3t[64 * 64];
    int t = threadIdx.x;
    for (int i = t; i < 8 * 64; i += 256) {
        int k = i >> 6, jj = i & 63;
        w1t[jj * 8 + k] = W1[i];
    }
    for (int i = t; i < 64 * 64; i += 256) {
        int k = i >> 6, jj = i & 63;
        w2t[jj * 64 + k] = W2[i];
        w3t[jj * 64 + k] = W3[i];
    }
    __syncthreads();
    int e = blockIdx.x * 256 + t;
    const float4* ep = (const float4*)(ef + (size_t)e * 8);
    float4 ea4 = ep[0], eb4 = ep[1];
    float h0[8] = {ea4.x, ea4.y, ea4.z, ea4.w, eb4.x, eb4.y, eb4.z, eb4.w};
    const float sc1 = 0.3535533905932738f;
#pragma unroll
    for (int k = 0; k < 8; ++k) h0[k] *= sc1;

    float ha[64], hb[64];
    for (int jj = 0; jj < 64; ++jj) {
        const float4* wr = (const float4*)(w1t + jj * 8);
        float4 wa = wr[0], wb = wr[1];
        float s = h0[0] * wa.x + h0[1] * wa.y + h0[2] * wa.z + h0[3] * wa.w
                + h0[4] * wb.x + h0[5] * wb.y + h0[6] * wb.z + h0[7] * wb.w;
        ha[jj] = silu2(s);
    }
    for (int jj = 0; jj < 64; ++jj) {
        const float4* wr = (const float4*)(w2t + jj * 64);
        float s = 0.f;
#pragma unroll
        for (int q = 0; q < 16; ++q) {
            float4 w = wr[q];
            s += ha[q * 4 + 0] * w.x + ha[q * 4 + 1] * w.y
               + ha[q * 4 + 2] * w.z + ha[q * 4 + 3] * w.w;
        }
        hb[jj] = silu2(s * 0.125f);
    }
    for (int jj = 0; jj < 64; ++jj) {
        const float4* wr = (const float4*)(w3t + jj * 64);
        float s = 0.f;
#pragma unroll
        for (int q = 0; q < 16; ++q) {
            float4 w = wr[q];
            s += hb[q * 4 + 0] * w.x + hb[q * 4 + 1] * w.y
               + hb[q * 4 + 2] * w.z + hb[q * 4 + 3] * w.w;
        }
        ha[jj] = silu2(s * 0.125f);
    }
    uint4* orow = (uint4*)(h3w + (size_t)e * 64);
#pragma unroll
    for (int q = 0; q < 8; ++q) {
        uint4 v;
        v.x = pack2(ha[q * 8 + 0], ha[q * 8 + 1]);
        v.y = pack2(ha[q * 8 + 2], ha[q * 8 + 3]);
        v.z = pack2(ha[q * 8 + 4], ha[q * 8 + 5]);
        v.w = pack2(ha[q * 8 + 6], ha[q * 8 + 7]);
        orow[q] = v;
    }
}

// ---------------------------------------------------------------------------
// K3: CSR build by receiver (zero -> histogram -> scan -> fill)
// ---------------------------------------------------------------------------
__global__ void k_zero(int* __restrict__ p, int n) {
    int i = blockIdx.x * 256 + threadIdx.x;
    if (i < n) p[i] = 0;
}
__global__ void k_hist(const int* __restrict__ ei, int* __restrict__ counts) {
    int e = blockIdx.x * 256 + threadIdx.x;
    if (e < NE) atomicAdd(&counts[ei[NE + e]], 1);
}
__global__ __launch_bounds__(1024) void k_scan(const int* __restrict__ counts,
                                               int* __restrict__ offs,
                                               int* __restrict__ cursor) {
    __shared__ int sums[1024];
    int t = threadIdx.x;
    int base = t * 10;
    int s = 0;
    for (int i = 0; i < 10; ++i) {
        int idx = base + i;
        if (idx < NN) s += counts[idx];
    }
    sums[t] = s;
    __syncthreads();
    for (int d = 1; d < 1024; d <<= 1) {
        int v = (t >= d) ? sums[t - d] : 0;
        __syncthreads();
        if (t >= d) sums[t] += v;
        __syncthreads();
    }
    int run = (t == 0) ? 0 : sums[t - 1];
    for (int i = 0; i < 10; ++i) {
        int idx = base + i;
        if (idx < NN) {
            offs[idx] = run;
            cursor[idx] = run;
            run += counts[idx];
        }
    }
    if (t == 0) offs[NN] = NE;
}
__global__ void k_fill(const int* __restrict__ ei, int* __restrict__ cursor,
                       int* __restrict__ elist) {
    int e = blockIdx.x * 256 + threadIdx.x;
    if (e < NE) {
        int slot = atomicAdd(&cursor[ei[NE + e]], 1);
        elist[slot] = e;
    }
}

// ---------------------------------------------------------------------------
// PATH A (big workspace): MFMA tpw GEMM.
// k_w4t: W4 (64x512 f32) -> w4T (512x64 bf16), one-time transpose.
// ---------------------------------------------------------------------------
__global__ void k_w4t(const float* __restrict__ W4, unsigned short* __restrict__ w4T) {
    int idx = blockIdx.x * 256 + threadIdx.x;   // 32768
    int k = idx >> 9, c = idx & 511;
    w4T[c * 64 + k] = f2bf(W4[idx]);
}

// k_tpw: tpw[e][c] = (h3[e] . W4[:,c]) / 8 via MFMA, computed as
// D = W4^T (M=512 cols) x h3^T (N=edges). Per wave: 64 edges x 512 cols.
// A-frag: lane holds A[m=lane&15][k=(lane>>4)*8+j] = w4T row (16B contig).
// B-frag: lane holds B[k=(lane>>4)*8+j][n=lane&15] = h3 row (16B contig).
// D: lane holds rows(cols) (lane>>4)*4+reg, col(edge) lane&15 -> packed 8B store.
// ---------------------------------------------------------------------------
__global__ __launch_bounds__(256) void k_tpw(const unsigned short* __restrict__ h3w,
                                             const unsigned short* __restrict__ w4T,
                                             unsigned short* __restrict__ tpw) {
    int wave = threadIdx.x >> 6, lane = threadIdx.x & 63;
    int e0 = blockIdx.x * 256 + wave * 64;
    int lm = lane & 15, lq = lane >> 4;
    uint4 B[4][2];
#pragma unroll
    for (int n = 0; n < 4; ++n)
#pragma unroll
        for (int k = 0; k < 2; ++k)
            B[n][k] = *(const uint4*)(h3w + (size_t)(e0 + n * 16 + lm) * 64 + k * 32 + lq * 8);
    const unsigned short* aw = w4T + lm * 64 + lq * 8;
    unsigned short* op = tpw + (size_t)e0 * 512;
#pragma unroll 2
    for (int m = 0; m < 32; ++m) {
        f32x4 acc0 = {0.f, 0.f, 0.f, 0.f};
        f32x4 acc1 = {0.f, 0.f, 0.f, 0.f};
        f32x4 acc2 = {0.f, 0.f, 0.f, 0.f};
        f32x4 acc3 = {0.f, 0.f, 0.f, 0.f};
#pragma unroll
        for (int k = 0; k < 2; ++k) {
            uint4 a_raw = *(const uint4*)(aw + m * 1024 + k * 32);
            short8 a = __builtin_bit_cast(short8, a_raw);
            acc0 = __builtin_amdgcn_mfma_f32_16x16x32_bf16(a, __builtin_bit_cast(short8, B[0][k]), acc0, 0, 0, 0);
            acc1 = __builtin_amdgcn_mfma_f32_16x16x32_bf16(a, __builtin_bit_cast(short8, B[1][k]), acc1, 0, 0, 0);
            acc2 = __builtin_amdgcn_mfma_f32_16x16x32_bf16(a, __builtin_bit_cast(short8, B[2][k]), acc2, 0, 0, 0);
            acc3 = __builtin_amdgcn_mfma_f32_16x16x32_bf16(a, __builtin_bit_cast(short8, B[3][k]), acc3, 0, 0, 0);
        }
        int cb = m * 16 + lq * 4;
        uint2 v;
        v.x = pack2(acc0[0] * 0.125f, acc0[1] * 0.125f);
        v.y = pack2(acc0[2] * 0.125f, acc0[3] * 0.125f);
        *(uint2*)(op + (size_t)(0 * 16 + lm) * 512 + cb) = v;
        v.x = pack2(acc1[0] * 0.125f, acc1[1] * 0.125f);
        v.y = pack2(acc1[2] * 0.125f, acc1[3] * 0.125f);
        *(uint2*)(op + (size_t)(1 * 16 + lm) * 512 + cb) = v;
        v.x = pack2(acc2[0] * 0.125f, acc2[1] * 0.125f);
        v.y = pack2(acc2[2] * 0.125f, acc2[3] * 0.125f);
        *(uint2*)(op + (size_t)(2 * 16 + lm) * 512 + cb) = v;
        v.x = pack2(acc3[0] * 0.125f, acc3[1] * 0.125f);
        v.y = pack2(acc3[2] * 0.125f, acc3[3] * 0.125f);
        *(uint2*)(op + (size_t)(3 * 16 + lm) * 512 + cb) = v;
    }
}

// ---------------------------------------------------------------------------
// PATH A k_msg2: tensor product + reduce, reading precomputed tpw.
// block = node, thread t -> cols (2t, 2t+1), j = t>>6 selects w1/w2/w3/w4.
// No LDS, ~6 accumulators -> high occupancy.
// ---------------------------------------------------------------------------
__global__ __launch_bounds__(256) void k_msg2(const float* __restrict__ xw,
                                              const unsigned short* __restrict__ tpw,
                                              const float* __restrict__ ea,
                                              const int* __restrict__ ei,
                                              const int* __restrict__ offs,
                                              const int* __restrict__ elist,
                                              unsigned short* __restrict__ msgb) {
    int n = blockIdx.x, t = threadIdx.x;
    int j = t >> 6, c0 = (t & 63) * 2;
    int beg = offs[n], end = offs[n + 1];
    float a0 = 0.f, a1 = 0.f, a2 = 0.f, a3 = 0.f, a4 = 0.f, a5 = 0.f;
    for (int i = beg; i < end; ++i) {
        int e = elist[i];
        int snd = ei[e];
        float4 eav = *(const float4*)(ea + (size_t)e * 4);
        float y0 = eav.x, y1x = eav.y, y1y = eav.z, y1z = eav.w;
        uint32_t wp = ((const uint32_t*)tpw)[(size_t)e * 256 + t];
        float wa = bflo(wp), wb = bfhi(wp);
        const float* xr = xw + (size_t)snd * 512;
        if (j == 0) {
            a0 += wa * xr[c0] * y0;
            a1 += wb * xr[c0 + 1] * y0;
        } else if (j == 1) {
            float ta = wa * xr[c0], tb = wb * xr[c0 + 1];
            a0 += ta * y1x; a1 += ta * y1y; a2 += ta * y1z;
            a3 += tb * y1x; a4 += tb * y1y; a5 += tb * y1z;
        } else if (j == 2) {
            float f0 = wa * y0, f1 = wb * y0;
            a0 += f0 * xr[128 + c0]; a1 += f0 * xr[256 + c0]; a2 += f0 * xr[384 + c0];
            a3 += f1 * xr[128 + c0 + 1]; a4 += f1 * xr[256 + c0 + 1]; a5 += f1 * xr[384 + c0 + 1];
        } else {
            float dta = xr[128 + c0] * y1x + xr[256 + c0] * y1y + xr[384 + c0] * y1z;
            float dtb = xr[128 + c0 + 1] * y1x + xr[256 + c0 + 1] * y1y + xr[384 + c0 + 1] * y1z;
            a0 += wa * dta * 0.5773502691896258f;
            a1 += wb * dtb * 0.5773502691896258f;
        }
    }
    unsigned short* mr = msgb + (size_t)n * 1024;
    if (j == 0) {
        *(uint32_t*)(mr + c0) = pack2(a0, a1);
    } else if (j == 1) {
        *(uint32_t*)(mr + 256 + c0)       = pack2(a0, a3);
        *(uint32_t*)(mr + 256 + 256 + c0) = pack2(a1, a4);
        *(uint32_t*)(mr + 256 + 512 + c0) = pack2(a2, a5);
    } else if (j == 2) {
        *(uint32_t*)(mr + 256 + 128 + c0)       = pack2(a0, a3);
        *(uint32_t*)(mr + 256 + 256 + 128 + c0) = pack2(a1, a4);
        *(uint32_t*)(mr + 256 + 512 + 128 + c0) = pack2(a2, a5);
    } else {
        *(uint32_t*)(mr + 128 + c0) = pack2(a0, a1);
    }
}

// ---------------------------------------------------------------------------
// PATH B fallback (round-3 proven, 140 VGPR no spill): fused W4 + reduce.
// ---------------------------------------------------------------------------
__global__ __launch_bounds__(256) void k_msg_fused(const float* __restrict__ xw,
                                                   const unsigned short* __restrict__ h3w,
                                                   const float* __restrict__ W4,
                                                   const float* __restrict__ ea,
                                                   const int* __restrict__ ei,
                                                   const int* __restrict__ offs,
                                                   const int* __restrict__ elist,
                                                   unsigned short* __restrict__ msgb) {
    __shared__ __align__(16) unsigned short w4s[64 * 512];
    int t = threadIdx.x;
    for (int i = t; i < 32768; i += 256) w4s[i] = f2bf(W4[i]);
    __syncthreads();
    int n = blockIdx.x;
    int j = t >> 6;
    int c0 = (t & 63) * 2;
    int wc = j * 128 + c0;
    int beg = offs[n], end = offs[n + 1];

    float a0 = 0.f, a1 = 0.f, a2 = 0.f, a3 = 0.f, a4 = 0.f, a5 = 0.f;

    for (int i = beg; i < end; ++i) {
        int e = elist[i];
        int snd = ei[e];
        float4 eavv = *(const float4*)(ea + (size_t)e * 4);
        float y0 = eavv.x, y1x = eavv.y, y1y = eavv.z, y1z = eavv.w;
        const uint4* hr = (const uint4*)(h3w + (size_t)e * 64);
        uint4 h[8];
#pragma unroll
        for (int q = 0; q < 8; ++q) h[q] = hr[q];

        float d0 = 0.f, d1 = 0.f;
#pragma unroll
        for (int q = 0; q < 8; ++q) {
            uint32_t hv;
            float hk0, hk1;
            uint32_t wv0, wv1;
#define DOT2(HV, KB)                                            \
            hv = (HV);                                          \
            hk0 = bflo(hv); hk1 = bfhi(hv);                     \
            wv0 = *(const uint32_t*)(w4s + (KB) * 512 + wc);    \
            wv1 = *(const uint32_t*)(w4s + ((KB) + 1) * 512 + wc); \
            d0 += hk0 * bflo(wv0); d1 += hk0 * bfhi(wv0);       \
            d0 += hk1 * bflo(wv1); d1 += hk1 * bfhi(wv1);
            DOT2(h[q].x, q * 8 + 0)
            DOT2(h[q].y, q * 8 + 2)
            DOT2(h[q].z, q * 8 + 4)
            DOT2(h[q].w, q * 8 + 6)
#undef DOT2
        }
        d0 *= 0.125f; d1 *= 0.125f;

        const float* xr = xw + (size_t)snd * 512;
        if (j == 0) {
            a0 += d0 * xr[c0] * y0;
            a1 += d1 * xr[c0 + 1] * y0;
        } else if (j == 1) {
            float ta = d0 * xr[c0], tb = d1 * xr[c0 + 1];
            a0 += ta * y1x; a1 += ta * y1y; a2 += ta * y1z;
            a3 += tb * y1x; a4 += tb * y1y; a5 += tb * y1z;
        } else if (j == 2) {
            float f0 = d0 * y0, f1 = d1 * y0;
            a0 += f0 * xr[128 + c0]; a1 += f0 * xr[256 + c0]; a2 += f0 * xr[384 + c0];
            a3 += f1 * xr[128 + c0 + 1]; a4 += f1 * xr[256 + c0 + 1]; a5 += f1 * xr[384 + c0 + 1];
        } else {
            float dta = xr[128 + c0] * y1x + xr[256 + c0] * y1y + xr[384 + c0] * y1z;
            float dtb = xr[128 + c0 + 1] * y1x + xr[256 + c0 + 1] * y1y + xr[384 + c0 + 1] * y1z;
            a0 += d0 * dta * 0.5773502691896258f;
            a1 += d1 * dtb * 0.5773502691896258f;
        }
    }

    unsigned short* mr = msgb + (size_t)n * 1024;
    if (j == 0) {
        *(uint32_t*)(mr + c0) = pack2(a0, a1);
    } else if (j == 1) {
        *(uint32_t*)(mr + 256 + c0)       = pack2(a0, a3);
        *(uint32_t*)(mr + 256 + 256 + c0) = pack2(a1, a4);
        *(uint32_t*)(mr + 256 + 512 + c0) = pack2(a2, a5);
    } else if (j == 2) {
        *(uint32_t*)(mr + 256 + 128 + c0)       = pack2(a0, a3);
        *(uint32_t*)(mr + 256 + 256 + 128 + c0) = pack2(a1, a4);
        *(uint32_t*)(mr + 256 + 512 + 128 + c0) = pack2(a2, a5);
    } else {
        *(uint32_t*)(mr + 128 + c0) = pack2(a0, a1);
    }
}

// ---------------------------------------------------------------------------
// K5a/K5b: output linears (weights staged f32->bf16 in LDS, 32 nodes/block)
// ---------------------------------------------------------------------------
__global__ __launch_bounds__(256) void k_out0(const unsigned short* __restrict__ msgb,
                                              const float* __restrict__ W,
                                              float* __restrict__ out) {
    __shared__ __align__(16) unsigned short wls[256 * 128];
    int t = threadIdx.x;
    {
        const float4* g = (const float4*)W;
        uint2* s2 = (uint2*)wls;
        for (int i = t; i < 8192; i += 256) {
            float4 v = g[i];
            s2[i] = make_uint2(pack2(v.x, v.y), pack2(v.z, v.w));
        }
    }
    __syncthreads();
    int v = t & 127, half = t >> 7;
    for (int jj = 0; jj < 16; ++jj) {
        int n = blockIdx.x * 32 + jj * 2 + half;
        if (n >= NN) break;
        const unsigned short* m0 = msgb + (size_t)n * 1024;
        float acc = 0.f;
#pragma unroll 8
        for (int u = 0; u < 256; ++u) acc += bf2f(m0[u]) * bf2f(wls[u * 128 + v]);
        out[(size_t)n * 512 + v] = acc * 0.00625f;
    }
}
__global__ __launch_bounds__(256) void k_out1(const unsigned short* __restrict__ msgb,
                                              const float* __restrict__ W,
                                              float* __restrict__ out) {
    __shared__ __align__(16) unsigned short wls[256 * 128];
    int t = threadIdx.x;
    {
        const float4* g = (const float4*)W;
        uint2* s2 = (uint2*)wls;
        for (int i = t; i < 8192; i += 256) {
            float4 v = g[i];
            s2[i] = make_uint2(pack2(v.x, v.y), pack2(v.z, v.w));
        }
    }
    __syncthreads();
    int v = t & 127, half = t >> 7;
    for (int jj = 0; jj < 16; ++jj) {
        int n = blockIdx.x * 32 + jj * 2 + half;
        if (n >= NN) break;
        const unsigned short* m1 = msgb + (size_t)n * 1024 + 256;
        float a0 = 0.f, a1 = 0.f, a2 = 0.f;
#pragma unroll 4
        for (int u = 0; u < 256; ++u) {
            float w = bf2f(wls[u * 128 + v]);
            a0 += bf2f(m1[u]) * w;
            a1 += bf2f(m1[256 + u]) * w;
            a2 += bf2f(m1[512 + u]) * w;
        }
        float* o = out + (size_t)n * 512 + 128 + v * 3;
        o[0] = a0 * 0.00625f;
        o[1] = a1 * 0.00625f;
        o[2] = a2 * 0.00625f;
    }
}

// ---------------------------------------------------------------------------
extern "C" void kernel_launch(void* const* d_in, const int* in_sizes, int n_in,
                              void* d_out, int out_size, void* d_ws, size_t ws_size,
                              hipStream_t stream) {
    const float* nf  = (const float*)d_in[0];
    const float* ea  = (const float*)d_in[1];
    const float* ef  = (const float*)d_in[2];
    const int*   ei  = (const int*)d_in[3];
    const float* Wu0 = (const float*)d_in[4];
    const float* Wu1 = (const float*)d_in[5];
    const float* W1  = (const float*)d_in[6];
    const float* W2  = (const float*)d_in[7];
    const float* W3  = (const float*)d_in[8];
    const float* W4  = (const float*)d_in[9];
    const float* Wo0 = (const float*)d_in[10];
    const float* Wo1 = (const float*)d_in[11];
    float* out = (float*)d_out;
    char* ws = (char*)d_ws;

    bool big = ws_size >= 226200000ull;   // deterministic across calls

    if (big) {
        // Layout A: tpw[0,163.84M) xw[163.84M) h3[184.32M) msg[204.8M)
        //           w4T[225.28M, +64K) CSR ints after  (end ~226.1 MB)
        unsigned short* tpw  = (unsigned short*)ws;
        float*          xw   = (float*)(ws + 163840000);
        unsigned short* h3w  = (unsigned short*)(ws + 184320000);
        unsigned short* msgb = (unsigned short*)(ws + 204800000);
        unsigned short* w4T  = (unsigned short*)(ws + 225280000);
        int* ib     = (int*)(ws + 225280000 + 65536);
        int* counts = ib;
        int* offs   = ib + 10240;
        int* cursor = ib + 20480;
        int* elist  = ib + 30720;

        k_up   <<<625, 256, 0, stream>>>(nf, Wu0, Wu1, xw);
        k_mlp_a<<<625, 256, 0, stream>>>(ef, W1, W2, W3, h3w);
        k_w4t  <<<128, 256, 0, stream>>>(W4, w4T);
        k_zero <<<40, 256, 0, stream>>>(counts, NN);
        k_hist <<<625, 256, 0, stream>>>(ei, counts);
        k_scan <<<1, 1024, 0, stream>>>(counts, offs, cursor);
        k_fill <<<625, 256, 0, stream>>>(ei, cursor, elist);
        k_tpw  <<<625, 256, 0, stream>>>(h3w, w4T, tpw);
        k_msg2 <<<NN, 256, 0, stream>>>(xw, tpw, ea, ei, offs, elist, msgb);
        k_out0 <<<313, 256, 0, stream>>>(msgb, Wo0, out);
        k_out1 <<<313, 256, 0, stream>>>(msgb, Wo1, out);
    } else {
        // Layout B (round-3 proven, ~62.2 MB)
        float*          xw   = (float*)ws;
        unsigned short* h3w  = (unsigned short*)(ws + 20480000);
        unsigned short* msgb = (unsigned short*)(ws + 40960000);
        int* ib     = (int*)(ws + 61440000);
        int* counts = ib;
        int* offs   = ib + 10240;
        int* cursor = ib + 20480;
        int* elist  = ib + 30720;

        k_up   <<<625, 256, 0, stream>>>(nf, Wu0, Wu1, xw);
        k_mlp_a<<<625, 256, 0, stream>>>(ef, W1, W2, W3, h3w);
        k_zero <<<40, 256, 0, stream>>>(counts, NN);
        k_hist <<<625, 256, 0, stream>>>(ei, counts);
        k_scan <<<1, 1024, 0, stream>>>(counts, offs, cursor);
        k_fill <<<625, 256, 0, stream>>>(ei, cursor, elist);
        k_msg_fused<<<NN, 256, 0, stream>>>(xw, h3w, W4, ea, ei, offs, elist, msgb);
        k_out0 <<<313, 256, 0, stream>>>(msgb, Wo0, out);
        k_out1 <<<313, 256, 0, stream>>>(msgb, Wo1, out);
    }
}

// Round 6
// 575.401 us; speedup vs baseline: 4.5817x; 1.4334x over previous
//
#include <hip/hip_runtime.h>
#include <stdint.h>

#define NN 10000
#define NE 160000

typedef short short8 __attribute__((ext_vector_type(8)));
typedef float f32x4 __attribute__((ext_vector_type(4)));

// ---------- bf16 helpers (internal staging format; I/O is f32) ----------
__device__ __forceinline__ float bf2f(unsigned short u) {
    return __uint_as_float(((uint32_t)u) << 16);
}
__device__ __forceinline__ float bflo(uint32_t u) { return __uint_as_float(u << 16); }
__device__ __forceinline__ float bfhi(uint32_t u) { return __uint_as_float(u & 0xffff0000u); }
__device__ __forceinline__ unsigned short f2bf(float f) {
    uint32_t u = __float_as_uint(f);
    u += 0x7fffu + ((u >> 16) & 1u);   // RNE
    return (unsigned short)(u >> 16);
}
__device__ __forceinline__ uint32_t pack2(float lo, float hi) {
    return (uint32_t)f2bf(lo) | ((uint32_t)f2bf(hi) << 16);
}
__device__ __forceinline__ float silu2(float x) {
    return 1.679177f * x / (1.f + __expf(-x));
}

// ---------------------------------------------------------------------------
// K1: up-projection.  xw[n] layout: [y0 (128) | y1 m-major: 128 + m*128 + v]
// ---------------------------------------------------------------------------
__global__ __launch_bounds__(256) void k_up(const float* __restrict__ nf,
                                            const float* __restrict__ Wu0,
                                            const float* __restrict__ Wu1,
                                            float* __restrict__ xw) {
    __shared__ __align__(16) unsigned short w0s[128 * 128];
    __shared__ __align__(16) unsigned short w1s[128 * 128];
    int t = threadIdx.x;
    {
        const float4* g0 = (const float4*)Wu0;
        const float4* g1 = (const float4*)Wu1;
        uint2* s0 = (uint2*)w0s;
        uint2* s1 = (uint2*)w1s;
        for (int i = t; i < 4096; i += 256) {
            float4 a = g0[i], b = g1[i];
            s0[i] = make_uint2(pack2(a.x, a.y), pack2(a.z, a.w));
            s1[i] = make_uint2(pack2(b.x, b.y), pack2(b.z, b.w));
        }
    }
    __syncthreads();
    int j = t & 3, g = t >> 2;
    bool ty0 = g < 16;
    int m = 0, v0;
    if (ty0) v0 = g << 3;
    else { int gg = g - 16; m = gg >> 4; v0 = (gg & 15) << 3; }
    const unsigned short* wbase = (ty0 ? w0s : w1s) + v0;
    int col = ty0 ? v0 : (128 + (m << 7) + v0);
    const float s = 0.08838834764831845f;   // 1/sqrt(128)

    for (int nq = 0; nq < 4; ++nq) {
        int n = blockIdx.x * 16 + nq * 4 + j;
        const float* xrow = nf + (size_t)n * 512;
        float acc[8] = {0, 0, 0, 0, 0, 0, 0, 0};
#pragma unroll 4
        for (int u = 0; u < 128; ++u) {
            uint4 wv = *(const uint4*)(wbase + u * 128);
            float xv = ty0 ? xrow[u] : xrow[128 + u * 3 + m];
            acc[0] += xv * bflo(wv.x); acc[1] += xv * bfhi(wv.x);
            acc[2] += xv * bflo(wv.y); acc[3] += xv * bfhi(wv.y);
            acc[4] += xv * bflo(wv.z); acc[5] += xv * bfhi(wv.z);
            acc[6] += xv * bflo(wv.w); acc[7] += xv * bfhi(wv.w);
        }
        float* o = xw + (size_t)n * 512 + col;
#pragma unroll
        for (int q = 0; q < 8; ++q) o[q] = acc[q] * s;
    }
}

// ---------------------------------------------------------------------------
// K2: edge MLP stages 1-3 -> h3 (NE x 64, bf16). one edge per thread.
// ---------------------------------------------------------------------------
__global__ __launch_bounds__(256) void k_mlp_a(const float* __restrict__ ef,
                                               const float* __restrict__ W1,
                                               const float* __restrict__ W2,
                                               const float* __restrict__ W3,
                                               unsigned short* __restrict__ h3w) {
    __shared__ float w1t[64 * 8];
    __shared__ float w2t[64 * 64];
    __shared__ float w3t[64 * 64];
    int t = threadIdx.x;
    for (int i = t; i < 8 * 64; i += 256) {
        int k = i >> 6, jj = i & 63;
        w1t[jj * 8 + k] = W1[i];
    }
    for (int i = t; i < 64 * 64; i += 256) {
        int k = i >> 6, jj = i & 63;
        w2t[jj * 64 + k] = W2[i];
        w3t[jj * 64 + k] = W3[i];
    }
    __syncthreads();
    int e = blockIdx.x * 256 + t;
    const float4* ep = (const float4*)(ef + (size_t)e * 8);
    float4 ea4 = ep[0], eb4 = ep[1];
    float h0[8] = {ea4.x, ea4.y, ea4.z, ea4.w, eb4.x, eb4.y, eb4.z, eb4.w};
    const float sc1 = 0.3535533905932738f;
#pragma unroll
    for (int k = 0; k < 8; ++k) h0[k] *= sc1;

    float ha[64], hb[64];
    for (int jj = 0; jj < 64; ++jj) {
        const float4* wr = (const float4*)(w1t + jj * 8);
        float4 wa = wr[0], wb = wr[1];
        float s = h0[0] * wa.x + h0[1] * wa.y + h0[2] * wa.z + h0[3] * wa.w
                + h0[4] * wb.x + h0[5] * wb.y + h0[6] * wb.z + h0[7] * wb.w;
        ha[jj] = silu2(s);
    }
    for (int jj = 0; jj < 64; ++jj) {
        const float4* wr = (const float4*)(w2t + jj * 64);
        float s = 0.f;
#pragma unroll
        for (int q = 0; q < 16; ++q) {
            float4 w = wr[q];
            s += ha[q * 4 + 0] * w.x + ha[q * 4 + 1] * w.y
               + ha[q * 4 + 2] * w.z + ha[q * 4 + 3] * w.w;
        }
        hb[jj] = silu2(s * 0.125f);
    }
    for (int jj = 0; jj < 64; ++jj) {
        const float4* wr = (const float4*)(w3t + jj * 64);
        float s = 0.f;
#pragma unroll
        for (int q = 0; q < 16; ++q) {
            float4 w = wr[q];
            s += hb[q * 4 + 0] * w.x + hb[q * 4 + 1] * w.y
               + hb[q * 4 + 2] * w.z + hb[q * 4 + 3] * w.w;
        }
        ha[jj] = silu2(s * 0.125f);
    }
    uint4* orow = (uint4*)(h3w + (size_t)e * 64);
#pragma unroll
    for (int q = 0; q < 8; ++q) {
        uint4 v;
        v.x = pack2(ha[q * 8 + 0], ha[q * 8 + 1]);
        v.y = pack2(ha[q * 8 + 2], ha[q * 8 + 3]);
        v.z = pack2(ha[q * 8 + 4], ha[q * 8 + 5]);
        v.w = pack2(ha[q * 8 + 6], ha[q * 8 + 7]);
        orow[q] = v;
    }
}

// ---------------------------------------------------------------------------
// K3: CSR build by receiver (zero -> histogram -> scan -> fill)
// ---------------------------------------------------------------------------
__global__ void k_zero(int* __restrict__ p, int n) {
    int i = blockIdx.x * 256 + threadIdx.x;
    if (i < n) p[i] = 0;
}
__global__ void k_hist(const int* __restrict__ ei, int* __restrict__ counts) {
    int e = blockIdx.x * 256 + threadIdx.x;
    if (e < NE) atomicAdd(&counts[ei[NE + e]], 1);
}
__global__ __launch_bounds__(1024) void k_scan(const int* __restrict__ counts,
                                               int* __restrict__ offs,
                                               int* __restrict__ cursor) {
    __shared__ int sums[1024];
    int t = threadIdx.x;
    int base = t * 10;
    int s = 0;
    for (int i = 0; i < 10; ++i) {
        int idx = base + i;
        if (idx < NN) s += counts[idx];
    }
    sums[t] = s;
    __syncthreads();
    for (int d = 1; d < 1024; d <<= 1) {
        int v = (t >= d) ? sums[t - d] : 0;
        __syncthreads();
        if (t >= d) sums[t] += v;
        __syncthreads();
    }
    int run = (t == 0) ? 0 : sums[t - 1];
    for (int i = 0; i < 10; ++i) {
        int idx = base + i;
        if (idx < NN) {
            offs[idx] = run;
            cursor[idx] = run;
            run += counts[idx];
        }
    }
    if (t == 0) offs[NN] = NE;
}
__global__ void k_fill(const int* __restrict__ ei, int* __restrict__ cursor,
                       int* __restrict__ elist) {
    int e = blockIdx.x * 256 + threadIdx.x;
    if (e < NE) {
        int slot = atomicAdd(&cursor[ei[NE + e]], 1);
        elist[slot] = e;
    }
}

// ---------------------------------------------------------------------------
// Weight transposes (bf16). k_w4t: W4 (64x512) -> w4T (512x64).
// k_wt2: Wo0/Wo1 (256x128) -> woT0/woT1 (128x256). Runs AFTER k_tpw
// because woT lives in the dead h3 region.
// ---------------------------------------------------------------------------
__global__ void k_w4t(const float* __restrict__ W4, unsigned short* __restrict__ w4T) {
    int idx = blockIdx.x * 256 + threadIdx.x;   // 32768
    int k = idx >> 9, c = idx & 511;
    w4T[c * 64 + k] = f2bf(W4[idx]);
}
__global__ void k_wt2(const float* __restrict__ Wo0, const float* __restrict__ Wo1,
                      unsigned short* __restrict__ woT0, unsigned short* __restrict__ woT1) {
    int idx = blockIdx.x * 256 + threadIdx.x;   // 32768
    int u = idx >> 7, v = idx & 127;
    woT0[v * 256 + u] = f2bf(Wo0[idx]);
    woT1[v * 256 + u] = f2bf(Wo1[idx]);
}

// ---------------------------------------------------------------------------
// k_tpw: tpw[e][c] = (h3[e] . W4[:,c]) / 8 via MFMA (HW-verified layouts, R5).
// ---------------------------------------------------------------------------
__global__ __launch_bounds__(256) void k_tpw(const unsigned short* __restrict__ h3w,
                                             const unsigned short* __restrict__ w4T,
                                             unsigned short* __restrict__ tpw) {
    int wave = threadIdx.x >> 6, lane = threadIdx.x & 63;
    int e0 = blockIdx.x * 256 + wave * 64;
    int lm = lane & 15, lq = lane >> 4;
    uint4 B[4][2];
#pragma unroll
    for (int n = 0; n < 4; ++n)
#pragma unroll
        for (int k = 0; k < 2; ++k)
            B[n][k] = *(const uint4*)(h3w + (size_t)(e0 + n * 16 + lm) * 64 + k * 32 + lq * 8);
    const unsigned short* aw = w4T + lm * 64 + lq * 8;
    unsigned short* op = tpw + (size_t)e0 * 512;
#pragma unroll 2
    for (int m = 0; m < 32; ++m) {
        f32x4 acc0 = {0.f, 0.f, 0.f, 0.f};
        f32x4 acc1 = {0.f, 0.f, 0.f, 0.f};
        f32x4 acc2 = {0.f, 0.f, 0.f, 0.f};
        f32x4 acc3 = {0.f, 0.f, 0.f, 0.f};
#pragma unroll
        for (int k = 0; k < 2; ++k) {
            uint4 a_raw = *(const uint4*)(aw + m * 1024 + k * 32);
            short8 a = __builtin_bit_cast(short8, a_raw);
            acc0 = __builtin_amdgcn_mfma_f32_16x16x32_bf16(a, __builtin_bit_cast(short8, B[0][k]), acc0, 0, 0, 0);
            acc1 = __builtin_amdgcn_mfma_f32_16x16x32_bf16(a, __builtin_bit_cast(short8, B[1][k]), acc1, 0, 0, 0);
            acc2 = __builtin_amdgcn_mfma_f32_16x16x32_bf16(a, __builtin_bit_cast(short8, B[2][k]), acc2, 0, 0, 0);
            acc3 = __builtin_amdgcn_mfma_f32_16x16x32_bf16(a, __builtin_bit_cast(short8, B[3][k]), acc3, 0, 0, 0);
        }
        int cb = m * 16 + lq * 4;
        uint2 v;
        v.x = pack2(acc0[0] * 0.125f, acc0[1] * 0.125f);
        v.y = pack2(acc0[2] * 0.125f, acc0[3] * 0.125f);
        *(uint2*)(op + (size_t)(0 * 16 + lm) * 512 + cb) = v;
        v.x = pack2(acc1[0] * 0.125f, acc1[1] * 0.125f);
        v.y = pack2(acc1[2] * 0.125f, acc1[3] * 0.125f);
        *(uint2*)(op + (size_t)(1 * 16 + lm) * 512 + cb) = v;
        v.x = pack2(acc2[0] * 0.125f, acc2[1] * 0.125f);
        v.y = pack2(acc2[2] * 0.125f, acc2[3] * 0.125f);
        *(uint2*)(op + (size_t)(2 * 16 + lm) * 512 + cb) = v;
        v.x = pack2(acc3[0] * 0.125f, acc3[1] * 0.125f);
        v.y = pack2(acc3[2] * 0.125f, acc3[3] * 0.125f);
        *(uint2*)(op + (size_t)(3 * 16 + lm) * 512 + cb) = v;
    }
}

// ---------------------------------------------------------------------------
// k_msg2: tensor product + reduce, reading precomputed tpw (R5 proven).
// ---------------------------------------------------------------------------
__global__ __launch_bounds__(256) void k_msg2(const float* __restrict__ xw,
                                              const unsigned short* __restrict__ tpw,
                                              const float* __restrict__ ea,
                                              const int* __restrict__ ei,
                                              const int* __restrict__ offs,
                                              const int* __restrict__ elist,
                                              unsigned short* __restrict__ msgb) {
    int n = blockIdx.x, t = threadIdx.x;
    int j = t >> 6, c0 = (t & 63) * 2;
    int beg = offs[n], end = offs[n + 1];
    float a0 = 0.f, a1 = 0.f, a2 = 0.f, a3 = 0.f, a4 = 0.f, a5 = 0.f;
    for (int i = beg; i < end; ++i) {
        int e = elist[i];
        int snd = ei[e];
        float4 eav = *(const float4*)(ea + (size_t)e * 4);
        float y0 = eav.x, y1x = eav.y, y1y = eav.z, y1z = eav.w;
        uint32_t wp = ((const uint32_t*)tpw)[(size_t)e * 256 + t];
        float wa = bflo(wp), wb = bfhi(wp);
        const float* xr = xw + (size_t)snd * 512;
        if (j == 0) {
            a0 += wa * xr[c0] * y0;
            a1 += wb * xr[c0 + 1] * y0;
        } else if (j == 1) {
            float ta = wa * xr[c0], tb = wb * xr[c0 + 1];
            a0 += ta * y1x; a1 += ta * y1y; a2 += ta * y1z;
            a3 += tb * y1x; a4 += tb * y1y; a5 += tb * y1z;
        } else if (j == 2) {
            float f0 = wa * y0, f1 = wb * y0;
            a0 += f0 * xr[128 + c0]; a1 += f0 * xr[256 + c0]; a2 += f0 * xr[384 + c0];
            a3 += f1 * xr[128 + c0 + 1]; a4 += f1 * xr[256 + c0 + 1]; a5 += f1 * xr[384 + c0 + 1];
        } else {
            float dta = xr[128 + c0] * y1x + xr[256 + c0] * y1y + xr[384 + c0] * y1z;
            float dtb = xr[128 + c0 + 1] * y1x + xr[256 + c0 + 1] * y1y + xr[384 + c0 + 1] * y1z;
            a0 += wa * dta * 0.5773502691896258f;
            a1 += wb * dtb * 0.5773502691896258f;
        }
    }
    unsigned short* mr = msgb + (size_t)n * 1024;
    if (j == 0) {
        *(uint32_t*)(mr + c0) = pack2(a0, a1);
    } else if (j == 1) {
        *(uint32_t*)(mr + 256 + c0)       = pack2(a0, a3);
        *(uint32_t*)(mr + 256 + 256 + c0) = pack2(a1, a4);
        *(uint32_t*)(mr + 256 + 512 + c0) = pack2(a2, a5);
    } else if (j == 2) {
        *(uint32_t*)(mr + 256 + 128 + c0)       = pack2(a0, a3);
        *(uint32_t*)(mr + 256 + 256 + 128 + c0) = pack2(a1, a4);
        *(uint32_t*)(mr + 256 + 512 + 128 + c0) = pack2(a2, a5);
    } else {
        *(uint32_t*)(mr + 128 + c0) = pack2(a0, a1);
    }
}

// ---------------------------------------------------------------------------
// k_out0 (MFMA): o0 = msg0 @ Wo0 /16/10.  M=10000 nodes, N=128, K=256.
// Wave = 16 nodes x 128 cols. A = msg0 rows [m][k]; B = woT0 rows [n][k];
// D: row=(lane>>4)*4+reg = node-in-tile, col=lane&15 = v-in-tile.
// ---------------------------------------------------------------------------
__global__ __launch_bounds__(256) void k_out0(const unsigned short* __restrict__ msgb,
                                              const unsigned short* __restrict__ woT,
                                              float* __restrict__ out) {
    int wave = threadIdx.x >> 6, lane = threadIdx.x & 63;
    int wid = blockIdx.x * 4 + wave;
    if (wid >= NN / 16) return;
    int n0 = wid * 16;
    int lm = lane & 15, lq = lane >> 4;
    uint4 A[8];
    const unsigned short* ar = msgb + (size_t)(n0 + lm) * 1024 + lq * 8;
#pragma unroll
    for (int kf = 0; kf < 8; ++kf) A[kf] = *(const uint4*)(ar + kf * 32);
    const unsigned short* br = woT + lm * 256 + lq * 8;
    float* ob = out + (size_t)n0 * 512;
    for (int vt = 0; vt < 8; ++vt) {
        f32x4 acc = {0.f, 0.f, 0.f, 0.f};
#pragma unroll
        for (int kf = 0; kf < 8; ++kf) {
            uint4 b = *(const uint4*)(br + vt * 16 * 256 + kf * 32);
            acc = __builtin_amdgcn_mfma_f32_16x16x32_bf16(
                __builtin_bit_cast(short8, A[kf]), __builtin_bit_cast(short8, b), acc, 0, 0, 0);
        }
#pragma unroll
        for (int r = 0; r < 4; ++r)
            ob[(size_t)(lq * 4 + r) * 512 + vt * 16 + lm] = acc[r] * 0.00625f;
    }
}

// ---------------------------------------------------------------------------
// k_out1 (MFMA): o1[n][v][m] = sum_u msg1[m][n][u] Wo1[u][v] /16/10,
// stored at out[n][128 + v*3 + m]. 3 GEMMs sharing B = woT1.
// ---------------------------------------------------------------------------
__global__ __launch_bounds__(256) void k_out1(const unsigned short* __restrict__ msgb,
                                              const unsigned short* __restrict__ woT,
                                              float* __restrict__ out) {
    int wave = threadIdx.x >> 6, lane = threadIdx.x & 63;
    int wid = blockIdx.x * 4 + wave;
    if (wid >= NN / 16) return;
    int n0 = wid * 16;
    int lm = lane & 15, lq = lane >> 4;
    uint4 A[3][8];
    const unsigned short* ar = msgb + (size_t)(n0 + lm) * 1024 + 256 + lq * 8;
#pragma unroll
    for (int m = 0; m < 3; ++m)
#pragma unroll
        for (int kf = 0; kf < 8; ++kf)
            A[m][kf] = *(const uint4*)(ar + m * 256 + kf * 32);
    const unsigned short* br = woT + lm * 256 + lq * 8;
    float* ob = out + (size_t)n0 * 512 + 128;
    for (int vt = 0; vt < 8; ++vt) {
        f32x4 acc[3];
#pragma unroll
        for (int m = 0; m < 3; ++m) acc[m] = (f32x4){0.f, 0.f, 0.f, 0.f};
#pragma unroll
        for (int kf = 0; kf < 8; ++kf) {
            uint4 braw = *(const uint4*)(br + vt * 16 * 256 + kf * 32);
            short8 b = __builtin_bit_cast(short8, braw);
#pragma unroll
            for (int m = 0; m < 3; ++m)
                acc[m] = __builtin_amdgcn_mfma_f32_16x16x32_bf16(
                    __builtin_bit_cast(short8, A[m][kf]), b, acc[m], 0, 0, 0);
        }
        int vb = (vt * 16 + lm) * 3;
#pragma unroll
        for (int r = 0; r < 4; ++r) {
            float* o = ob + (size_t)(lq * 4 + r) * 512 + vb;
            o[0] = acc[0][r] * 0.00625f;
            o[1] = acc[1][r] * 0.00625f;
            o[2] = acc[2][r] * 0.00625f;
        }
    }
}

// ---------------------------------------------------------------------------
extern "C" void kernel_launch(void* const* d_in, const int* in_sizes, int n_in,
                              void* d_out, int out_size, void* d_ws, size_t ws_size,
                              hipStream_t stream) {
    const float* nf  = (const float*)d_in[0];
    const float* ea  = (const float*)d_in[1];
    const float* ef  = (const float*)d_in[2];
    const int*   ei  = (const int*)d_in[3];
    const float* Wu0 = (const float*)d_in[4];
    const float* Wu1 = (const float*)d_in[5];
    const float* W1  = (const float*)d_in[6];
    const float* W2  = (const float*)d_in[7];
    const float* W3  = (const float*)d_in[8];
    const float* W4  = (const float*)d_in[9];
    const float* Wo0 = (const float*)d_in[10];
    const float* Wo1 = (const float*)d_in[11];
    float* out = (float*)d_out;
    char* ws = (char*)d_ws;

    // Layout (ws >= 226.2 MB proven in R5):
    //   tpw [0, 163.84M)  xw [163.84M, 184.32M)  h3 [184.32M, 204.8M)
    //   msg [204.8M, 225.28M)  w4T [225.28M, +64K)  CSR ints after.
    //   woT0/woT1 alias the h3 region (h3 dead after k_tpw; k_wt2 runs after).
    unsigned short* tpw  = (unsigned short*)ws;
    float*          xw   = (float*)(ws + 163840000);
    unsigned short* h3w  = (unsigned short*)(ws + 184320000);
    unsigned short* woT0 = (unsigned short*)(ws + 184320000);
    unsigned short* woT1 = (unsigned short*)(ws + 184320000 + 65536);
    unsigned short* msgb = (unsigned short*)(ws + 204800000);
    unsigned short* w4T  = (unsigned short*)(ws + 225280000);
    int* ib     = (int*)(ws + 225280000 + 65536);
    int* counts = ib;
    int* offs   = ib + 10240;
    int* cursor = ib + 20480;
    int* elist  = ib + 30720;

    k_up   <<<625, 256, 0, stream>>>(nf, Wu0, Wu1, xw);
    k_mlp_a<<<625, 256, 0, stream>>>(ef, W1, W2, W3, h3w);
    k_w4t  <<<128, 256, 0, stream>>>(W4, w4T);
    k_zero <<<40, 256, 0, stream>>>(counts, NN);
    k_hist <<<625, 256, 0, stream>>>(ei, counts);
    k_scan <<<1, 1024, 0, stream>>>(counts, offs, cursor);
    k_fill <<<625, 256, 0, stream>>>(ei, cursor, elist);
    k_tpw  <<<625, 256, 0, stream>>>(h3w, w4T, tpw);
    k_wt2  <<<128, 256, 0, stream>>>(Wo0, Wo1, woT0, woT1);   // after k_tpw: reuses h3 space
    k_msg2 <<<NN, 256, 0, stream>>>(xw, tpw, ea, ei, offs, elist, msgb);
    k_out0 <<<157, 256, 0, stream>>>(msgb, woT0, out);
    k_out1 <<<157, 256, 0, stream>>>(msgb, woT1, out);
}

// Round 7
// 465.046 us; speedup vs baseline: 5.6690x; 1.2373x over previous
//
#include <hip/hip_runtime.h>
#include <stdint.h>

#define NN 10000
#define NE 160000

typedef short short8 __attribute__((ext_vector_type(8)));
typedef float f32x4 __attribute__((ext_vector_type(4)));

// ---------- bf16 helpers (internal staging format; I/O is f32) ----------
__device__ __forceinline__ float bf2f(unsigned short u) {
    return __uint_as_float(((uint32_t)u) << 16);
}
__device__ __forceinline__ float bflo(uint32_t u) { return __uint_as_float(u << 16); }
__device__ __forceinline__ float bfhi(uint32_t u) { return __uint_as_float(u & 0xffff0000u); }
__device__ __forceinline__ unsigned short f2bf(float f) {
    uint32_t u = __float_as_uint(f);
    u += 0x7fffu + ((u >> 16) & 1u);   // RNE
    return (unsigned short)(u >> 16);
}
__device__ __forceinline__ uint32_t pack2(float lo, float hi) {
    return (uint32_t)f2bf(lo) | ((uint32_t)f2bf(hi) << 16);
}
__device__ __forceinline__ float silu2(float x) {
    return 1.679177f * x / (1.f + __expf(-x));
}

// ---------------------------------------------------------------------------
// K1: up-projection.  xw[n] layout: [y0 (128) | y1 m-major: 128 + m*128 + v]
// ---------------------------------------------------------------------------
__global__ __launch_bounds__(256) void k_up(const float* __restrict__ nf,
                                            const float* __restrict__ Wu0,
                                            const float* __restrict__ Wu1,
                                            float* __restrict__ xw) {
    __shared__ __align__(16) unsigned short w0s[128 * 128];
    __shared__ __align__(16) unsigned short w1s[128 * 128];
    int t = threadIdx.x;
    {
        const float4* g0 = (const float4*)Wu0;
        const float4* g1 = (const float4*)Wu1;
        uint2* s0 = (uint2*)w0s;
        uint2* s1 = (uint2*)w1s;
        for (int i = t; i < 4096; i += 256) {
            float4 a = g0[i], b = g1[i];
            s0[i] = make_uint2(pack2(a.x, a.y), pack2(a.z, a.w));
            s1[i] = make_uint2(pack2(b.x, b.y), pack2(b.z, b.w));
        }
    }
    __syncthreads();
    int j = t & 3, g = t >> 2;
    bool ty0 = g < 16;
    int m = 0, v0;
    if (ty0) v0 = g << 3;
    else { int gg = g - 16; m = gg >> 4; v0 = (gg & 15) << 3; }
    const unsigned short* wbase = (ty0 ? w0s : w1s) + v0;
    int col = ty0 ? v0 : (128 + (m << 7) + v0);
    const float s = 0.08838834764831845f;   // 1/sqrt(128)

    for (int nq = 0; nq < 4; ++nq) {
        int n = blockIdx.x * 16 + nq * 4 + j;
        const float* xrow = nf + (size_t)n * 512;
        float acc[8] = {0, 0, 0, 0, 0, 0, 0, 0};
#pragma unroll 4
        for (int u = 0; u < 128; ++u) {
            uint4 wv = *(const uint4*)(wbase + u * 128);
            float xv = ty0 ? xrow[u] : xrow[128 + u * 3 + m];
            acc[0] += xv * bflo(wv.x); acc[1] += xv * bfhi(wv.x);
            acc[2] += xv * bflo(wv.y); acc[3] += xv * bfhi(wv.y);
            acc[4] += xv * bflo(wv.z); acc[5] += xv * bfhi(wv.z);
            acc[6] += xv * bflo(wv.w); acc[7] += xv * bfhi(wv.w);
        }
        float* o = xw + (size_t)n * 512 + col;
#pragma unroll
        for (int q = 0; q < 8; ++q) o[q] = acc[q] * s;
    }
}

// ---------------------------------------------------------------------------
// k_wmlp: pre-transpose+scale MLP weights to bf16.
//   w1Tp[jj][k] (64x32, k>=8 zero) = W1[k][jj] / sqrt(8)
//   w2T [jj][k] (64x64)            = W2[k][jj] / 8
//   w3T [jj][k] (64x64)            = W3[k][jj] / 8
// ---------------------------------------------------------------------------
__global__ __launch_bounds__(256) void k_wmlp(const float* __restrict__ W1,
                                              const float* __restrict__ W2,
                                              const float* __restrict__ W3,
                                              unsigned short* __restrict__ w1Tp,
                                              unsigned short* __restrict__ w2T,
                                              unsigned short* __restrict__ w3T) {
    int t = threadIdx.x;
    for (int i = t; i < 2048; i += 256) {
        int jj = i >> 5, k = i & 31;
        w1Tp[i] = (k < 8) ? f2bf(W1[k * 64 + jj] * 0.3535533905932738f) : 0;
    }
    for (int i = t; i < 4096; i += 256) {
        int jj = i >> 6, k = i & 63;
        w2T[i] = f2bf(W2[k * 64 + jj] * 0.125f);
        w3T[i] = f2bf(W3[k * 64 + jj] * 0.125f);
    }
}

// ---------------------------------------------------------------------------
// K2 (MFMA): edge MLP stages 1-3 -> h3 (NE x 64 bf16).
// Wave = 64 edges. Each stage: D = Wt (M=64 ch) x h (N=64 edges), K=32/64.
// D-layout -> B-frag layout via per-wave LDS (stride 72 shorts: b128-aligned,
// conflict-floor). Wave-private LDS => in-order DS pipe, no barriers needed.
// silu applied on D fragments in registers; scales folded into weights.
// ---------------------------------------------------------------------------
__global__ __launch_bounds__(256) void k_mlp(const float* __restrict__ ef,
                                             const unsigned short* __restrict__ w1Tp,
                                             const unsigned short* __restrict__ w2T,
                                             const unsigned short* __restrict__ w3T,
                                             unsigned short* __restrict__ h3w) {
    __shared__ __align__(16) unsigned short hs_all[4][64 * 72];
    int wave = threadIdx.x >> 6, lane = threadIdx.x & 63;
    int lm = lane & 15, lq = lane >> 4;
    int e0 = blockIdx.x * 256 + wave * 64;
    unsigned short* h = hs_all[wave];

    // ---------------- stage 1: K=32 (8 real, zero-padded) ----------------
    uint4 A1[4];
#pragma unroll
    for (int mt = 0; mt < 4; ++mt)
        A1[mt] = *(const uint4*)(w1Tp + (mt * 16 + lm) * 32 + lq * 8);
#pragma unroll
    for (int nt = 0; nt < 4; ++nt) {
        uint4 b = {0, 0, 0, 0};
        if (lq == 0) {
            const float4* p = (const float4*)(ef + (size_t)(e0 + nt * 16 + lm) * 8);
            float4 x = p[0], y = p[1];
            b.x = pack2(x.x, x.y); b.y = pack2(x.z, x.w);
            b.z = pack2(y.x, y.y); b.w = pack2(y.z, y.w);
        }
        short8 bb = __builtin_bit_cast(short8, b);
        unsigned short* hrow = h + (nt * 16 + lm) * 72;
#pragma unroll
        for (int mt = 0; mt < 4; ++mt) {
            f32x4 acc = {0.f, 0.f, 0.f, 0.f};
            acc = __builtin_amdgcn_mfma_f32_16x16x32_bf16(
                __builtin_bit_cast(short8, A1[mt]), bb, acc, 0, 0, 0);
            uint2 v;
            v.x = pack2(silu2(acc[0]), silu2(acc[1]));
            v.y = pack2(silu2(acc[2]), silu2(acc[3]));
            *(uint2*)(hrow + mt * 16 + lq * 4) = v;
        }
    }

    // ---------------- stage 2: K=64 ----------------
    uint4 A2[4][2];
#pragma unroll
    for (int mt = 0; mt < 4; ++mt)
#pragma unroll
        for (int kf = 0; kf < 2; ++kf)
            A2[mt][kf] = *(const uint4*)(w2T + (mt * 16 + lm) * 64 + kf * 32 + lq * 8);
#pragma unroll
    for (int nt = 0; nt < 4; ++nt) {
        unsigned short* hrow = h + (nt * 16 + lm) * 72;
        short8 B0 = __builtin_bit_cast(short8, *(const uint4*)(hrow + lq * 8));
        short8 B1 = __builtin_bit_cast(short8, *(const uint4*)(hrow + 32 + lq * 8));
#pragma unroll
        for (int mt = 0; mt < 4; ++mt) {
            f32x4 acc = {0.f, 0.f, 0.f, 0.f};
            acc = __builtin_amdgcn_mfma_f32_16x16x32_bf16(
                __builtin_bit_cast(short8, A2[mt][0]), B0, acc, 0, 0, 0);
            acc = __builtin_amdgcn_mfma_f32_16x16x32_bf16(
                __builtin_bit_cast(short8, A2[mt][1]), B1, acc, 0, 0, 0);
            uint2 v;
            v.x = pack2(silu2(acc[0]), silu2(acc[1]));
            v.y = pack2(silu2(acc[2]), silu2(acc[3]));
            *(uint2*)(hrow + mt * 16 + lq * 4) = v;
        }
    }

    // ---------------- stage 3: K=64 ----------------
    uint4 A3[4][2];
#pragma unroll
    for (int mt = 0; mt < 4; ++mt)
#pragma unroll
        for (int kf = 0; kf < 2; ++kf)
            A3[mt][kf] = *(const uint4*)(w3T + (mt * 16 + lm) * 64 + kf * 32 + lq * 8);
#pragma unroll
    for (int nt = 0; nt < 4; ++nt) {
        unsigned short* hrow = h + (nt * 16 + lm) * 72;
        short8 B0 = __builtin_bit_cast(short8, *(const uint4*)(hrow + lq * 8));
        short8 B1 = __builtin_bit_cast(short8, *(const uint4*)(hrow + 32 + lq * 8));
#pragma unroll
        for (int mt = 0; mt < 4; ++mt) {
            f32x4 acc = {0.f, 0.f, 0.f, 0.f};
            acc = __builtin_amdgcn_mfma_f32_16x16x32_bf16(
                __builtin_bit_cast(short8, A3[mt][0]), B0, acc, 0, 0, 0);
            acc = __builtin_amdgcn_mfma_f32_16x16x32_bf16(
                __builtin_bit_cast(short8, A3[mt][1]), B1, acc, 0, 0, 0);
            uint2 v;
            v.x = pack2(silu2(acc[0]), silu2(acc[1]));
            v.y = pack2(silu2(acc[2]), silu2(acc[3]));
            *(uint2*)(hrow + mt * 16 + lq * 4) = v;
        }
    }

    // ---------------- flush: coalesced 16B/lane stores ----------------
    const unsigned short* hr = h + lane * 72;
    uint4* og = (uint4*)(h3w + (size_t)(e0 + lane) * 64);
#pragma unroll
    for (int q = 0; q < 8; ++q) og[q] = *(const uint4*)(hr + q * 8);
}

// ---------------------------------------------------------------------------
// K3: CSR build by receiver (zero -> histogram -> scan -> fill)
// ---------------------------------------------------------------------------
__global__ void k_zero(int* __restrict__ p, int n) {
    int i = blockIdx.x * 256 + threadIdx.x;
    if (i < n) p[i] = 0;
}
__global__ void k_hist(const int* __restrict__ ei, int* __restrict__ counts) {
    int e = blockIdx.x * 256 + threadIdx.x;
    if (e < NE) atomicAdd(&counts[ei[NE + e]], 1);
}
__global__ __launch_bounds__(1024) void k_scan(const int* __restrict__ counts,
                                               int* __restrict__ offs,
                                               int* __restrict__ cursor) {
    __shared__ int sums[1024];
    int t = threadIdx.x;
    int base = t * 10;
    int s = 0;
    for (int i = 0; i < 10; ++i) {
        int idx = base + i;
        if (idx < NN) s += counts[idx];
    }
    sums[t] = s;
    __syncthreads();
    for (int d = 1; d < 1024; d <<= 1) {
        int v = (t >= d) ? sums[t - d] : 0;
        __syncthreads();
        if (t >= d) sums[t] += v;
        __syncthreads();
    }
    int run = (t == 0) ? 0 : sums[t - 1];
    for (int i = 0; i < 10; ++i) {
        int idx = base + i;
        if (idx < NN) {
            offs[idx] = run;
            cursor[idx] = run;
            run += counts[idx];
        }
    }
    if (t == 0) offs[NN] = NE;
}
__global__ void k_fill(const int* __restrict__ ei, int* __restrict__ cursor,
                       int* __restrict__ elist) {
    int e = blockIdx.x * 256 + threadIdx.x;
    if (e < NE) {
        int slot = atomicAdd(&cursor[ei[NE + e]], 1);
        elist[slot] = e;
    }
}

// ---------------------------------------------------------------------------
// Weight transposes (bf16). k_w4t: W4 (64x512) -> w4T (512x64).
// k_wt2: Wo0/Wo1 (256x128) -> woT0/woT1 (128x256). Runs AFTER k_tpw
// because woT lives in the dead h3 region.
// ---------------------------------------------------------------------------
__global__ void k_w4t(const float* __restrict__ W4, unsigned short* __restrict__ w4T) {
    int idx = blockIdx.x * 256 + threadIdx.x;   // 32768
    int k = idx >> 9, c = idx & 511;
    w4T[c * 64 + k] = f2bf(W4[idx]);
}
__global__ void k_wt2(const float* __restrict__ Wo0, const float* __restrict__ Wo1,
                      unsigned short* __restrict__ woT0, unsigned short* __restrict__ woT1) {
    int idx = blockIdx.x * 256 + threadIdx.x;   // 32768
    int u = idx >> 7, v = idx & 127;
    woT0[v * 256 + u] = f2bf(Wo0[idx]);
    woT1[v * 256 + u] = f2bf(Wo1[idx]);
}

// ---------------------------------------------------------------------------
// k_tpw: tpw[e][c] = (h3[e] . W4[:,c]) / 8 via MFMA (HW-verified layouts, R5).
// ---------------------------------------------------------------------------
__global__ __launch_bounds__(256) void k_tpw(const unsigned short* __restrict__ h3w,
                                             const unsigned short* __restrict__ w4T,
                                             unsigned short* __restrict__ tpw) {
    int wave = threadIdx.x >> 6, lane = threadIdx.x & 63;
    int e0 = blockIdx.x * 256 + wave * 64;
    int lm = lane & 15, lq = lane >> 4;
    uint4 B[4][2];
#pragma unroll
    for (int n = 0; n < 4; ++n)
#pragma unroll
        for (int k = 0; k < 2; ++k)
            B[n][k] = *(const uint4*)(h3w + (size_t)(e0 + n * 16 + lm) * 64 + k * 32 + lq * 8);
    const unsigned short* aw = w4T + lm * 64 + lq * 8;
    unsigned short* op = tpw + (size_t)e0 * 512;
#pragma unroll 2
    for (int m = 0; m < 32; ++m) {
        f32x4 acc0 = {0.f, 0.f, 0.f, 0.f};
        f32x4 acc1 = {0.f, 0.f, 0.f, 0.f};
        f32x4 acc2 = {0.f, 0.f, 0.f, 0.f};
        f32x4 acc3 = {0.f, 0.f, 0.f, 0.f};
#pragma unroll
        for (int k = 0; k < 2; ++k) {
            uint4 a_raw = *(const uint4*)(aw + m * 1024 + k * 32);
            short8 a = __builtin_bit_cast(short8, a_raw);
            acc0 = __builtin_amdgcn_mfma_f32_16x16x32_bf16(a, __builtin_bit_cast(short8, B[0][k]), acc0, 0, 0, 0);
            acc1 = __builtin_amdgcn_mfma_f32_16x16x32_bf16(a, __builtin_bit_cast(short8, B[1][k]), acc1, 0, 0, 0);
            acc2 = __builtin_amdgcn_mfma_f32_16x16x32_bf16(a, __builtin_bit_cast(short8, B[2][k]), acc2, 0, 0, 0);
            acc3 = __builtin_amdgcn_mfma_f32_16x16x32_bf16(a, __builtin_bit_cast(short8, B[3][k]), acc3, 0, 0, 0);
        }
        int cb = m * 16 + lq * 4;
        uint2 v;
        v.x = pack2(acc0[0] * 0.125f, acc0[1] * 0.125f);
        v.y = pack2(acc0[2] * 0.125f, acc0[3] * 0.125f);
        *(uint2*)(op + (size_t)(0 * 16 + lm) * 512 + cb) = v;
        v.x = pack2(acc1[0] * 0.125f, acc1[1] * 0.125f);
        v.y = pack2(acc1[2] * 0.125f, acc1[3] * 0.125f);
        *(uint2*)(op + (size_t)(1 * 16 + lm) * 512 + cb) = v;
        v.x = pack2(acc2[0] * 0.125f, acc2[1] * 0.125f);
        v.y = pack2(acc2[2] * 0.125f, acc2[3] * 0.125f);
        *(uint2*)(op + (size_t)(2 * 16 + lm) * 512 + cb) = v;
        v.x = pack2(acc3[0] * 0.125f, acc3[1] * 0.125f);
        v.y = pack2(acc3[2] * 0.125f, acc3[3] * 0.125f);
        *(uint2*)(op + (size_t)(3 * 16 + lm) * 512 + cb) = v;
    }
}

// ---------------------------------------------------------------------------
// k_msg2: tensor product + reduce, reading precomputed tpw (R5 proven).
// ---------------------------------------------------------------------------
__global__ __launch_bounds__(256) void k_msg2(const float* __restrict__ xw,
                                              const unsigned short* __restrict__ tpw,
                                              const float* __restrict__ ea,
                                              const int* __restrict__ ei,
                                              const int* __restrict__ offs,
                                              const int* __restrict__ elist,
                                              unsigned short* __restrict__ msgb) {
    int n = blockIdx.x, t = threadIdx.x;
    int j = t >> 6, c0 = (t & 63) * 2;
    int beg = offs[n], end = offs[n + 1];
    float a0 = 0.f, a1 = 0.f, a2 = 0.f, a3 = 0.f, a4 = 0.f, a5 = 0.f;
    for (int i = beg; i < end; ++i) {
        int e = elist[i];
        int snd = ei[e];
        float4 eav = *(const float4*)(ea + (size_t)e * 4);
        float y0 = eav.x, y1x = eav.y, y1y = eav.z, y1z = eav.w;
        uint32_t wp = ((const uint32_t*)tpw)[(size_t)e * 256 + t];
        float wa = bflo(wp), wb = bfhi(wp);
        const float* xr = xw + (size_t)snd * 512;
        if (j == 0) {
            a0 += wa * xr[c0] * y0;
            a1 += wb * xr[c0 + 1] * y0;
        } else if (j == 1) {
            float ta = wa * xr[c0], tb = wb * xr[c0 + 1];
            a0 += ta * y1x; a1 += ta * y1y; a2 += ta * y1z;
            a3 += tb * y1x; a4 += tb * y1y; a5 += tb * y1z;
        } else if (j == 2) {
            float f0 = wa * y0, f1 = wb * y0;
            a0 += f0 * xr[128 + c0]; a1 += f0 * xr[256 + c0]; a2 += f0 * xr[384 + c0];
            a3 += f1 * xr[128 + c0 + 1]; a4 += f1 * xr[256 + c0 + 1]; a5 += f1 * xr[384 + c0 + 1];
        } else {
            float dta = xr[128 + c0] * y1x + xr[256 + c0] * y1y + xr[384 + c0] * y1z;
            float dtb = xr[128 + c0 + 1] * y1x + xr[256 + c0 + 1] * y1y + xr[384 + c0 + 1] * y1z;
            a0 += wa * dta * 0.5773502691896258f;
            a1 += wb * dtb * 0.5773502691896258f;
        }
    }
    unsigned short* mr = msgb + (size_t)n * 1024;
    if (j == 0) {
        *(uint32_t*)(mr + c0) = pack2(a0, a1);
    } else if (j == 1) {
        *(uint32_t*)(mr + 256 + c0)       = pack2(a0, a3);
        *(uint32_t*)(mr + 256 + 256 + c0) = pack2(a1, a4);
        *(uint32_t*)(mr + 256 + 512 + c0) = pack2(a2, a5);
    } else if (j == 2) {
        *(uint32_t*)(mr + 256 + 128 + c0)       = pack2(a0, a3);
        *(uint32_t*)(mr + 256 + 256 + 128 + c0) = pack2(a1, a4);
        *(uint32_t*)(mr + 256 + 512 + 128 + c0) = pack2(a2, a5);
    } else {
        *(uint32_t*)(mr + 128 + c0) = pack2(a0, a1);
    }
}

// ---------------------------------------------------------------------------
// k_out0 (MFMA): o0 = msg0 @ Wo0 /16/10.  M=10000 nodes, N=128, K=256.
// ---------------------------------------------------------------------------
__global__ __launch_bounds__(256) void k_out0(const unsigned short* __restrict__ msgb,
                                              const unsigned short* __restrict__ woT,
                                              float* __restrict__ out) {
    int wave = threadIdx.x >> 6, lane = threadIdx.x & 63;
    int wid = blockIdx.x * 4 + wave;
    if (wid >= NN / 16) return;
    int n0 = wid * 16;
    int lm = lane & 15, lq = lane >> 4;
    uint4 A[8];
    const unsigned short* ar = msgb + (size_t)(n0 + lm) * 1024 + lq * 8;
#pragma unroll
    for (int kf = 0; kf < 8; ++kf) A[kf] = *(const uint4*)(ar + kf * 32);
    const unsigned short* br = woT + lm * 256 + lq * 8;
    float* ob = out + (size_t)n0 * 512;
    for (int vt = 0; vt < 8; ++vt) {
        f32x4 acc = {0.f, 0.f, 0.f, 0.f};
#pragma unroll
        for (int kf = 0; kf < 8; ++kf) {
            uint4 b = *(const uint4*)(br + vt * 16 * 256 + kf * 32);
            acc = __builtin_amdgcn_mfma_f32_16x16x32_bf16(
                __builtin_bit_cast(short8, A[kf]), __builtin_bit_cast(short8, b), acc, 0, 0, 0);
        }
#pragma unroll
        for (int r = 0; r < 4; ++r)
            ob[(size_t)(lq * 4 + r) * 512 + vt * 16 + lm] = acc[r] * 0.00625f;
    }
}

// ---------------------------------------------------------------------------
// k_out1 (MFMA): o1[n][v][m] = sum_u msg1[m][n][u] Wo1[u][v] /16/10,
// stored at out[n][128 + v*3 + m]. 3 GEMMs sharing B = woT1.
// ---------------------------------------------------------------------------
__global__ __launch_bounds__(256) void k_out1(const unsigned short* __restrict__ msgb,
                                              const unsigned short* __restrict__ woT,
                                              float* __restrict__ out) {
    int wave = threadIdx.x >> 6, lane = threadIdx.x & 63;
    int wid = blockIdx.x * 4 + wave;
    if (wid >= NN / 16) return;
    int n0 = wid * 16;
    int lm = lane & 15, lq = lane >> 4;
    uint4 A[3][8];
    const unsigned short* ar = msgb + (size_t)(n0 + lm) * 1024 + 256 + lq * 8;
#pragma unroll
    for (int m = 0; m < 3; ++m)
#pragma unroll
        for (int kf = 0; kf < 8; ++kf)
            A[m][kf] = *(const uint4*)(ar + m * 256 + kf * 32);
    const unsigned short* br = woT + lm * 256 + lq * 8;
    float* ob = out + (size_t)n0 * 512 + 128;
    for (int vt = 0; vt < 8; ++vt) {
        f32x4 acc[3];
#pragma unroll
        for (int m = 0; m < 3; ++m) acc[m] = (f32x4){0.f, 0.f, 0.f, 0.f};
#pragma unroll
        for (int kf = 0; kf < 8; ++kf) {
            uint4 braw = *(const uint4*)(br + vt * 16 * 256 + kf * 32);
            short8 b = __builtin_bit_cast(short8, braw);
#pragma unroll
            for (int m = 0; m < 3; ++m)
                acc[m] = __builtin_amdgcn_mfma_f32_16x16x32_bf16(
                    __builtin_bit_cast(short8, A[m][kf]), b, acc[m], 0, 0, 0);
        }
        int vb = (vt * 16 + lm) * 3;
#pragma unroll
        for (int r = 0; r < 4; ++r) {
            float* o = ob + (size_t)(lq * 4 + r) * 512 + vb;
            o[0] = acc[0][r] * 0.00625f;
            o[1] = acc[1][r] * 0.00625f;
            o[2] = acc[2][r] * 0.00625f;
        }
    }
}

// ---------------------------------------------------------------------------
extern "C" void kernel_launch(void* const* d_in, const int* in_sizes, int n_in,
                              void* d_out, int out_size, void* d_ws, size_t ws_size,
                              hipStream_t stream) {
    const float* nf  = (const float*)d_in[0];
    const float* ea  = (const float*)d_in[1];
    const float* ef  = (const float*)d_in[2];
    const int*   ei  = (const int*)d_in[3];
    const float* Wu0 = (const float*)d_in[4];
    const float* Wu1 = (const float*)d_in[5];
    const float* W1  = (const float*)d_in[6];
    const float* W2  = (const float*)d_in[7];
    const float* W3  = (const float*)d_in[8];
    const float* W4  = (const float*)d_in[9];
    const float* Wo0 = (const float*)d_in[10];
    const float* Wo1 = (const float*)d_in[11];
    float* out = (float*)d_out;
    char* ws = (char*)d_ws;

    // Layout (ws >= 226.2 MB proven in R5):
    //   tpw [0, 163.84M)  xw [163.84M, 184.32M)  h3 [184.32M, 204.8M)
    //   msg [204.8M, 225.28M)  w4T [225.28M, +64K)  CSR ints  MLP weights.
    //   woT0/woT1 alias the h3 region (h3 dead after k_tpw; k_wt2 runs after).
    unsigned short* tpw  = (unsigned short*)ws;
    float*          xw   = (float*)(ws + 163840000);
    unsigned short* h3w  = (unsigned short*)(ws + 184320000);
    unsigned short* woT0 = (unsigned short*)(ws + 184320000);
    unsigned short* woT1 = (unsigned short*)(ws + 184320000 + 65536);
    unsigned short* msgb = (unsigned short*)(ws + 204800000);
    unsigned short* w4T  = (unsigned short*)(ws + 225280000);
    int* ib     = (int*)(ws + 225280000 + 65536);
    int* counts = ib;                        // NN
    int* offs   = ib + 10240;                // NN+1
    int* cursor = ib + 20480;                // NN
    int* elist  = ib + 30720;                // NE  (ends at int 190720)
    unsigned short* w1Tp = (unsigned short*)(ws + 226108416);          // 64x32
    unsigned short* w2T  = (unsigned short*)(ws + 226108416 + 4096);   // 64x64
    unsigned short* w3T  = (unsigned short*)(ws + 226108416 + 12288);  // 64x64

    k_wmlp <<<1, 256, 0, stream>>>(W1, W2, W3, w1Tp, w2T, w3T);
    k_up   <<<625, 256, 0, stream>>>(nf, Wu0, Wu1, xw);
    k_mlp  <<<625, 256, 0, stream>>>(ef, w1Tp, w2T, w3T, h3w);
    k_w4t  <<<128, 256, 0, stream>>>(W4, w4T);
    k_zero <<<40, 256, 0, stream>>>(counts, NN);
    k_hist <<<625, 256, 0, stream>>>(ei, counts);
    k_scan <<<1, 1024, 0, stream>>>(counts, offs, cursor);
    k_fill <<<625, 256, 0, stream>>>(ei, cursor, elist);
    k_tpw  <<<625, 256, 0, stream>>>(h3w, w4T, tpw);
    k_wt2  <<<128, 256, 0, stream>>>(Wo0, Wo1, woT0, woT1);   // after k_tpw: reuses h3 space
    k_msg2 <<<NN, 256, 0, stream>>>(xw, tpw, ea, ei, offs, elist, msgb);
    k_out0 <<<157, 256, 0, stream>>>(msgb, woT0, out);
    k_out1 <<<157, 256, 0, stream>>>(msgb, woT1, out);
}

// Round 8
// 457.724 us; speedup vs baseline: 5.7596x; 1.0160x over previous
//
#include <hip/hip_runtime.h>
#include <stdint.h>

#define NN 10000
#define NE 160000

typedef short short8 __attribute__((ext_vector_type(8)));
typedef float f32x4 __attribute__((ext_vector_type(4)));

// ---------- bf16 helpers (internal staging format; I/O is f32) ----------
__device__ __forceinline__ float bf2f(unsigned short u) {
    return __uint_as_float(((uint32_t)u) << 16);
}
__device__ __forceinline__ float bflo(uint32_t u) { return __uint_as_float(u << 16); }
__device__ __forceinline__ float bfhi(uint32_t u) { return __uint_as_float(u & 0xffff0000u); }
__device__ __forceinline__ unsigned short f2bf(float f) {
    uint32_t u = __float_as_uint(f);
    u += 0x7fffu + ((u >> 16) & 1u);   // RNE
    return (unsigned short)(u >> 16);
}
__device__ __forceinline__ uint32_t pack2(float lo, float hi) {
    return (uint32_t)f2bf(lo) | ((uint32_t)f2bf(hi) << 16);
}
__device__ __forceinline__ float silu2(float x) {
    return 1.679177f * x / (1.f + __expf(-x));
}

// ---------------------------------------------------------------------------
// K1: up-projection.  xw[n] layout: [y0 (128) | y1 m-major: 128 + m*128 + v]
// ---------------------------------------------------------------------------
__global__ __launch_bounds__(256) void k_up(const float* __restrict__ nf,
                                            const float* __restrict__ Wu0,
                                            const float* __restrict__ Wu1,
                                            float* __restrict__ xw) {
    __shared__ __align__(16) unsigned short w0s[128 * 128];
    __shared__ __align__(16) unsigned short w1s[128 * 128];
    int t = threadIdx.x;
    {
        const float4* g0 = (const float4*)Wu0;
        const float4* g1 = (const float4*)Wu1;
        uint2* s0 = (uint2*)w0s;
        uint2* s1 = (uint2*)w1s;
        for (int i = t; i < 4096; i += 256) {
            float4 a = g0[i], b = g1[i];
            s0[i] = make_uint2(pack2(a.x, a.y), pack2(a.z, a.w));
            s1[i] = make_uint2(pack2(b.x, b.y), pack2(b.z, b.w));
        }
    }
    __syncthreads();
    int j = t & 3, g = t >> 2;
    bool ty0 = g < 16;
    int m = 0, v0;
    if (ty0) v0 = g << 3;
    else { int gg = g - 16; m = gg >> 4; v0 = (gg & 15) << 3; }
    const unsigned short* wbase = (ty0 ? w0s : w1s) + v0;
    int col = ty0 ? v0 : (128 + (m << 7) + v0);
    const float s = 0.08838834764831845f;   // 1/sqrt(128)

    for (int nq = 0; nq < 4; ++nq) {
        int n = blockIdx.x * 16 + nq * 4 + j;
        const float* xrow = nf + (size_t)n * 512;
        float acc[8] = {0, 0, 0, 0, 0, 0, 0, 0};
#pragma unroll 4
        for (int u = 0; u < 128; ++u) {
            uint4 wv = *(const uint4*)(wbase + u * 128);
            float xv = ty0 ? xrow[u] : xrow[128 + u * 3 + m];
            acc[0] += xv * bflo(wv.x); acc[1] += xv * bfhi(wv.x);
            acc[2] += xv * bflo(wv.y); acc[3] += xv * bfhi(wv.y);
            acc[4] += xv * bflo(wv.z); acc[5] += xv * bfhi(wv.z);
            acc[6] += xv * bflo(wv.w); acc[7] += xv * bfhi(wv.w);
        }
        float* o = xw + (size_t)n * 512 + col;
#pragma unroll
        for (int q = 0; q < 8; ++q) o[q] = acc[q] * s;
    }
}

// ---------------------------------------------------------------------------
// k_wmlp: pre-transpose+scale MLP weights to bf16.
// ---------------------------------------------------------------------------
__global__ __launch_bounds__(256) void k_wmlp(const float* __restrict__ W1,
                                              const float* __restrict__ W2,
                                              const float* __restrict__ W3,
                                              unsigned short* __restrict__ w1Tp,
                                              unsigned short* __restrict__ w2T,
                                              unsigned short* __restrict__ w3T) {
    int t = threadIdx.x;
    for (int i = t; i < 2048; i += 256) {
        int jj = i >> 5, k = i & 31;
        w1Tp[i] = (k < 8) ? f2bf(W1[k * 64 + jj] * 0.3535533905932738f) : 0;
    }
    for (int i = t; i < 4096; i += 256) {
        int jj = i >> 6, k = i & 63;
        w2T[i] = f2bf(W2[k * 64 + jj] * 0.125f);
        w3T[i] = f2bf(W3[k * 64 + jj] * 0.125f);
    }
}

// ---------------------------------------------------------------------------
// K2 (MFMA): edge MLP stages 1-3 -> h3 (NE x 64 bf16). (R7 proven)
// ---------------------------------------------------------------------------
__global__ __launch_bounds__(256) void k_mlp(const float* __restrict__ ef,
                                             const unsigned short* __restrict__ w1Tp,
                                             const unsigned short* __restrict__ w2T,
                                             const unsigned short* __restrict__ w3T,
                                             unsigned short* __restrict__ h3w) {
    __shared__ __align__(16) unsigned short hs_all[4][64 * 72];
    int wave = threadIdx.x >> 6, lane = threadIdx.x & 63;
    int lm = lane & 15, lq = lane >> 4;
    int e0 = blockIdx.x * 256 + wave * 64;
    unsigned short* h = hs_all[wave];

    // stage 1: K=32 (8 real, zero-padded)
    uint4 A1[4];
#pragma unroll
    for (int mt = 0; mt < 4; ++mt)
        A1[mt] = *(const uint4*)(w1Tp + (mt * 16 + lm) * 32 + lq * 8);
#pragma unroll
    for (int nt = 0; nt < 4; ++nt) {
        uint4 b = {0, 0, 0, 0};
        if (lq == 0) {
            const float4* p = (const float4*)(ef + (size_t)(e0 + nt * 16 + lm) * 8);
            float4 x = p[0], y = p[1];
            b.x = pack2(x.x, x.y); b.y = pack2(x.z, x.w);
            b.z = pack2(y.x, y.y); b.w = pack2(y.z, y.w);
        }
        short8 bb = __builtin_bit_cast(short8, b);
        unsigned short* hrow = h + (nt * 16 + lm) * 72;
#pragma unroll
        for (int mt = 0; mt < 4; ++mt) {
            f32x4 acc = {0.f, 0.f, 0.f, 0.f};
            acc = __builtin_amdgcn_mfma_f32_16x16x32_bf16(
                __builtin_bit_cast(short8, A1[mt]), bb, acc, 0, 0, 0);
            uint2 v;
            v.x = pack2(silu2(acc[0]), silu2(acc[1]));
            v.y = pack2(silu2(acc[2]), silu2(acc[3]));
            *(uint2*)(hrow + mt * 16 + lq * 4) = v;
        }
    }

    // stage 2: K=64
    uint4 A2[4][2];
#pragma unroll
    for (int mt = 0; mt < 4; ++mt)
#pragma unroll
        for (int kf = 0; kf < 2; ++kf)
            A2[mt][kf] = *(const uint4*)(w2T + (mt * 16 + lm) * 64 + kf * 32 + lq * 8);
#pragma unroll
    for (int nt = 0; nt < 4; ++nt) {
        unsigned short* hrow = h + (nt * 16 + lm) * 72;
        short8 B0 = __builtin_bit_cast(short8, *(const uint4*)(hrow + lq * 8));
        short8 B1 = __builtin_bit_cast(short8, *(const uint4*)(hrow + 32 + lq * 8));
#pragma unroll
        for (int mt = 0; mt < 4; ++mt) {
            f32x4 acc = {0.f, 0.f, 0.f, 0.f};
            acc = __builtin_amdgcn_mfma_f32_16x16x32_bf16(
                __builtin_bit_cast(short8, A2[mt][0]), B0, acc, 0, 0, 0);
            acc = __builtin_amdgcn_mfma_f32_16x16x32_bf16(
                __builtin_bit_cast(short8, A2[mt][1]), B1, acc, 0, 0, 0);
            uint2 v;
            v.x = pack2(silu2(acc[0]), silu2(acc[1]));
            v.y = pack2(silu2(acc[2]), silu2(acc[3]));
            *(uint2*)(hrow + mt * 16 + lq * 4) = v;
        }
    }

    // stage 3: K=64
    uint4 A3[4][2];
#pragma unroll
    for (int mt = 0; mt < 4; ++mt)
#pragma unroll
        for (int kf = 0; kf < 2; ++kf)
            A3[mt][kf] = *(const uint4*)(w3T + (mt * 16 + lm) * 64 + kf * 32 + lq * 8);
#pragma unroll
    for (int nt = 0; nt < 4; ++nt) {
        unsigned short* hrow = h + (nt * 16 + lm) * 72;
        short8 B0 = __builtin_bit_cast(short8, *(const uint4*)(hrow + lq * 8));
        short8 B1 = __builtin_bit_cast(short8, *(const uint4*)(hrow + 32 + lq * 8));
#pragma unroll
        for (int mt = 0; mt < 4; ++mt) {
            f32x4 acc = {0.f, 0.f, 0.f, 0.f};
            acc = __builtin_amdgcn_mfma_f32_16x16x32_bf16(
                __builtin_bit_cast(short8, A3[mt][0]), B0, acc, 0, 0, 0);
            acc = __builtin_amdgcn_mfma_f32_16x16x32_bf16(
                __builtin_bit_cast(short8, A3[mt][1]), B1, acc, 0, 0, 0);
            uint2 v;
            v.x = pack2(silu2(acc[0]), silu2(acc[1]));
            v.y = pack2(silu2(acc[2]), silu2(acc[3]));
            *(uint2*)(hrow + mt * 16 + lq * 4) = v;
        }
    }

    // flush: coalesced 16B/lane stores
    const unsigned short* hr = h + lane * 72;
    uint4* og = (uint4*)(h3w + (size_t)(e0 + lane) * 64);
#pragma unroll
    for (int q = 0; q < 8; ++q) og[q] = *(const uint4*)(hr + q * 8);
}

// ---------------------------------------------------------------------------
// K3: CSR build by receiver (zero -> histogram -> scan -> fill)
// ---------------------------------------------------------------------------
__global__ void k_zero(int* __restrict__ p, int n) {
    int i = blockIdx.x * 256 + threadIdx.x;
    if (i < n) p[i] = 0;
}
__global__ void k_hist(const int* __restrict__ ei, int* __restrict__ counts) {
    int e = blockIdx.x * 256 + threadIdx.x;
    if (e < NE) atomicAdd(&counts[ei[NE + e]], 1);
}
__global__ __launch_bounds__(1024) void k_scan(const int* __restrict__ counts,
                                               int* __restrict__ offs,
                                               int* __restrict__ cursor) {
    __shared__ int sums[1024];
    int t = threadIdx.x;
    int base = t * 10;
    int s = 0;
    for (int i = 0; i < 10; ++i) {
        int idx = base + i;
        if (idx < NN) s += counts[idx];
    }
    sums[t] = s;
    __syncthreads();
    for (int d = 1; d < 1024; d <<= 1) {
        int v = (t >= d) ? sums[t - d] : 0;
        __syncthreads();
        if (t >= d) sums[t] += v;
        __syncthreads();
    }
    int run = (t == 0) ? 0 : sums[t - 1];
    for (int i = 0; i < 10; ++i) {
        int idx = base + i;
        if (idx < NN) {
            offs[idx] = run;
            cursor[idx] = run;
            run += counts[idx];
        }
    }
    if (t == 0) offs[NN] = NE;
}
__global__ void k_fill(const int* __restrict__ ei, int* __restrict__ cursor,
                       int* __restrict__ elist) {
    int e = blockIdx.x * 256 + threadIdx.x;
    if (e < NE) {
        int slot = atomicAdd(&cursor[ei[NE + e]], 1);
        elist[slot] = e;
    }
}
// k_gather: resolve per-slot sender + edge_attrs (runs after k_tpw; lives in dead h3)
__global__ void k_gather(const int* __restrict__ ei, const float* __restrict__ ea,
                         const int* __restrict__ elist,
                         int* __restrict__ eis, float4* __restrict__ eap) {
    int i = blockIdx.x * 256 + threadIdx.x;
    if (i < NE) {
        int e = elist[i];
        eis[i] = ei[e];
        eap[i] = *(const float4*)(ea + (size_t)e * 4);
    }
}

// ---------------------------------------------------------------------------
// Weight transposes (bf16).
// ---------------------------------------------------------------------------
__global__ void k_w4t(const float* __restrict__ W4, unsigned short* __restrict__ w4T) {
    int idx = blockIdx.x * 256 + threadIdx.x;   // 32768
    int k = idx >> 9, c = idx & 511;
    w4T[c * 64 + k] = f2bf(W4[idx]);
}
__global__ void k_wt2(const float* __restrict__ Wo0, const float* __restrict__ Wo1,
                      unsigned short* __restrict__ woT0, unsigned short* __restrict__ woT1) {
    int idx = blockIdx.x * 256 + threadIdx.x;   // 32768
    int u = idx >> 7, v = idx & 127;
    woT0[v * 256 + u] = f2bf(Wo0[idx]);
    woT1[v * 256 + u] = f2bf(Wo1[idx]);
}

// ---------------------------------------------------------------------------
// k_tpw (PERMUTED): tpw_perm[slot] = (h3[elist[slot]] . W4[:,c]) / 8 via MFMA.
// Gathered h3 reads (random 128B over 20MB, L2/L3-resident); sequential writes.
// k_msg2 then streams tpw_perm contiguously per receiver range.
// ---------------------------------------------------------------------------
__global__ __launch_bounds__(256) void k_tpw(const unsigned short* __restrict__ h3w,
                                             const unsigned short* __restrict__ w4T,
                                             const int* __restrict__ elist,
                                             unsigned short* __restrict__ tpw) {
    int wave = threadIdx.x >> 6, lane = threadIdx.x & 63;
    int e0 = blockIdx.x * 256 + wave * 64;
    int lm = lane & 15, lq = lane >> 4;
    uint4 B[4][2];
#pragma unroll
    for (int n = 0; n < 4; ++n) {
        int esrc = elist[e0 + n * 16 + lm];
#pragma unroll
        for (int k = 0; k < 2; ++k)
            B[n][k] = *(const uint4*)(h3w + (size_t)esrc * 64 + k * 32 + lq * 8);
    }
    const unsigned short* aw = w4T + lm * 64 + lq * 8;
    unsigned short* op = tpw + (size_t)e0 * 512;
#pragma unroll 2
    for (int m = 0; m < 32; ++m) {
        f32x4 acc0 = {0.f, 0.f, 0.f, 0.f};
        f32x4 acc1 = {0.f, 0.f, 0.f, 0.f};
        f32x4 acc2 = {0.f, 0.f, 0.f, 0.f};
        f32x4 acc3 = {0.f, 0.f, 0.f, 0.f};
#pragma unroll
        for (int k = 0; k < 2; ++k) {
            uint4 a_raw = *(const uint4*)(aw + m * 1024 + k * 32);
            short8 a = __builtin_bit_cast(short8, a_raw);
            acc0 = __builtin_amdgcn_mfma_f32_16x16x32_bf16(a, __builtin_bit_cast(short8, B[0][k]), acc0, 0, 0, 0);
            acc1 = __builtin_amdgcn_mfma_f32_16x16x32_bf16(a, __builtin_bit_cast(short8, B[1][k]), acc1, 0, 0, 0);
            acc2 = __builtin_amdgcn_mfma_f32_16x16x32_bf16(a, __builtin_bit_cast(short8, B[2][k]), acc2, 0, 0, 0);
            acc3 = __builtin_amdgcn_mfma_f32_16x16x32_bf16(a, __builtin_bit_cast(short8, B[3][k]), acc3, 0, 0, 0);
        }
        int cb = m * 16 + lq * 4;
        uint2 v;
        v.x = pack2(acc0[0] * 0.125f, acc0[1] * 0.125f);
        v.y = pack2(acc0[2] * 0.125f, acc0[3] * 0.125f);
        *(uint2*)(op + (size_t)(0 * 16 + lm) * 512 + cb) = v;
        v.x = pack2(acc1[0] * 0.125f, acc1[1] * 0.125f);
        v.y = pack2(acc1[2] * 0.125f, acc1[3] * 0.125f);
        *(uint2*)(op + (size_t)(1 * 16 + lm) * 512 + cb) = v;
        v.x = pack2(acc2[0] * 0.125f, acc2[1] * 0.125f);
        v.y = pack2(acc2[2] * 0.125f, acc2[3] * 0.125f);
        *(uint2*)(op + (size_t)(2 * 16 + lm) * 512 + cb) = v;
        v.x = pack2(acc3[0] * 0.125f, acc3[1] * 0.125f);
        v.y = pack2(acc3[2] * 0.125f, acc3[3] * 0.125f);
        *(uint2*)(op + (size_t)(3 * 16 + lm) * 512 + cb) = v;
    }
}

// ---------------------------------------------------------------------------
// k_msg2: tensor product + reduce. tpw/eis/eap now SEQUENTIAL per block range.
// Only remaining random access: xw sender-row gather (20 MB, L3-resident).
// ---------------------------------------------------------------------------
__global__ __launch_bounds__(256) void k_msg2(const float* __restrict__ xw,
                                              const unsigned short* __restrict__ tpw,
                                              const int* __restrict__ eis,
                                              const float4* __restrict__ eap,
                                              const int* __restrict__ offs,
                                              unsigned short* __restrict__ msgb) {
    int n = blockIdx.x, t = threadIdx.x;
    int j = t >> 6, c0 = (t & 63) * 2;
    int beg = offs[n], end = offs[n + 1];
    float a0 = 0.f, a1 = 0.f, a2 = 0.f, a3 = 0.f, a4 = 0.f, a5 = 0.f;
    for (int i = beg; i < end; ++i) {
        int snd = eis[i];
        float4 eav = eap[i];
        float y0 = eav.x, y1x = eav.y, y1y = eav.z, y1z = eav.w;
        uint32_t wp = ((const uint32_t*)tpw)[(size_t)i * 256 + t];
        float wa = bflo(wp), wb = bfhi(wp);
        const float* xr = xw + (size_t)snd * 512;
        if (j == 0) {
            a0 += wa * xr[c0] * y0;
            a1 += wb * xr[c0 + 1] * y0;
        } else if (j == 1) {
            float ta = wa * xr[c0], tb = wb * xr[c0 + 1];
            a0 += ta * y1x; a1 += ta * y1y; a2 += ta * y1z;
            a3 += tb * y1x; a4 += tb * y1y; a5 += tb * y1z;
        } else if (j == 2) {
            float f0 = wa * y0, f1 = wb * y0;
            a0 += f0 * xr[128 + c0]; a1 += f0 * xr[256 + c0]; a2 += f0 * xr[384 + c0];
            a3 += f1 * xr[128 + c0 + 1]; a4 += f1 * xr[256 + c0 + 1]; a5 += f1 * xr[384 + c0 + 1];
        } else {
            float dta = xr[128 + c0] * y1x + xr[256 + c0] * y1y + xr[384 + c0] * y1z;
            float dtb = xr[128 + c0 + 1] * y1x + xr[256 + c0 + 1] * y1y + xr[384 + c0 + 1] * y1z;
            a0 += wa * dta * 0.5773502691896258f;
            a1 += wb * dtb * 0.5773502691896258f;
        }
    }
    unsigned short* mr = msgb + (size_t)n * 1024;
    if (j == 0) {
        *(uint32_t*)(mr + c0) = pack2(a0, a1);
    } else if (j == 1) {
        *(uint32_t*)(mr + 256 + c0)       = pack2(a0, a3);
        *(uint32_t*)(mr + 256 + 256 + c0) = pack2(a1, a4);
        *(uint32_t*)(mr + 256 + 512 + c0) = pack2(a2, a5);
    } else if (j == 2) {
        *(uint32_t*)(mr + 256 + 128 + c0)       = pack2(a0, a3);
        *(uint32_t*)(mr + 256 + 256 + 128 + c0) = pack2(a1, a4);
        *(uint32_t*)(mr + 256 + 512 + 128 + c0) = pack2(a2, a5);
    } else {
        *(uint32_t*)(mr + 128 + c0) = pack2(a0, a1);
    }
}

// ---------------------------------------------------------------------------
// k_out0 (MFMA): o0 = msg0 @ Wo0 /16/10.  M=10000 nodes, N=128, K=256.
// ---------------------------------------------------------------------------
__global__ __launch_bounds__(256) void k_out0(const unsigned short* __restrict__ msgb,
                                              const unsigned short* __restrict__ woT,
                                              float* __restrict__ out) {
    int wave = threadIdx.x >> 6, lane = threadIdx.x & 63;
    int wid = blockIdx.x * 4 + wave;
    if (wid >= NN / 16) return;
    int n0 = wid * 16;
    int lm = lane & 15, lq = lane >> 4;
    uint4 A[8];
    const unsigned short* ar = msgb + (size_t)(n0 + lm) * 1024 + lq * 8;
#pragma unroll
    for (int kf = 0; kf < 8; ++kf) A[kf] = *(const uint4*)(ar + kf * 32);
    const unsigned short* br = woT + lm * 256 + lq * 8;
    float* ob = out + (size_t)n0 * 512;
    for (int vt = 0; vt < 8; ++vt) {
        f32x4 acc = {0.f, 0.f, 0.f, 0.f};
#pragma unroll
        for (int kf = 0; kf < 8; ++kf) {
            uint4 b = *(const uint4*)(br + vt * 16 * 256 + kf * 32);
            acc = __builtin_amdgcn_mfma_f32_16x16x32_bf16(
                __builtin_bit_cast(short8, A[kf]), __builtin_bit_cast(short8, b), acc, 0, 0, 0);
        }
#pragma unroll
        for (int r = 0; r < 4; ++r)
            ob[(size_t)(lq * 4 + r) * 512 + vt * 16 + lm] = acc[r] * 0.00625f;
    }
}

// ---------------------------------------------------------------------------
// k_out1 (MFMA): 3 GEMMs sharing B = woT1 -> out[n][128 + v*3 + m].
// ---------------------------------------------------------------------------
__global__ __launch_bounds__(256) void k_out1(const unsigned short* __restrict__ msgb,
                                              const unsigned short* __restrict__ woT,
                                              float* __restrict__ out) {
    int wave = threadIdx.x >> 6, lane = threadIdx.x & 63;
    int wid = blockIdx.x * 4 + wave;
    if (wid >= NN / 16) return;
    int n0 = wid * 16;
    int lm = lane & 15, lq = lane >> 4;
    uint4 A[3][8];
    const unsigned short* ar = msgb + (size_t)(n0 + lm) * 1024 + 256 + lq * 8;
#pragma unroll
    for (int m = 0; m < 3; ++m)
#pragma unroll
        for (int kf = 0; kf < 8; ++kf)
            A[m][kf] = *(const uint4*)(ar + m * 256 + kf * 32);
    const unsigned short* br = woT + lm * 256 + lq * 8;
    float* ob = out + (size_t)n0 * 512 + 128;
    for (int vt = 0; vt < 8; ++vt) {
        f32x4 acc[3];
#pragma unroll
        for (int m = 0; m < 3; ++m) acc[m] = (f32x4){0.f, 0.f, 0.f, 0.f};
#pragma unroll
        for (int kf = 0; kf < 8; ++kf) {
            uint4 braw = *(const uint4*)(br + vt * 16 * 256 + kf * 32);
            short8 b = __builtin_bit_cast(short8, braw);
#pragma unroll
            for (int m = 0; m < 3; ++m)
                acc[m] = __builtin_amdgcn_mfma_f32_16x16x32_bf16(
                    __builtin_bit_cast(short8, A[m][kf]), b, acc[m], 0, 0, 0);
        }
        int vb = (vt * 16 + lm) * 3;
#pragma unroll
        for (int r = 0; r < 4; ++r) {
            float* o = ob + (size_t)(lq * 4 + r) * 512 + vb;
            o[0] = acc[0][r] * 0.00625f;
            o[1] = acc[1][r] * 0.00625f;
            o[2] = acc[2][r] * 0.00625f;
        }
    }
}

// ---------------------------------------------------------------------------
extern "C" void kernel_launch(void* const* d_in, const int* in_sizes, int n_in,
                              void* d_out, int out_size, void* d_ws, size_t ws_size,
                              hipStream_t stream) {
    const float* nf  = (const float*)d_in[0];
    const float* ea  = (const float*)d_in[1];
    const float* ef  = (const float*)d_in[2];
    const int*   ei  = (const int*)d_in[3];
    const float* Wu0 = (const float*)d_in[4];
    const float* Wu1 = (const float*)d_in[5];
    const float* W1  = (const float*)d_in[6];
    const float* W2  = (const float*)d_in[7];
    const float* W3  = (const float*)d_in[8];
    const float* W4  = (const float*)d_in[9];
    const float* Wo0 = (const float*)d_in[10];
    const float* Wo1 = (const float*)d_in[11];
    float* out = (float*)d_out;
    char* ws = (char*)d_ws;

    // Layout (ws >= 226.2 MB proven):
    //   tpw [0, 163.84M)  xw [163.84M, 184.32M)  h3 [184.32M, 204.8M)
    //   msg [204.8M, 225.28M)  w4T [225.28M, +64K)  CSR ints  MLP weights.
    //   woT0/woT1 + eis/eap alias the h3 region (dead after k_tpw).
    unsigned short* tpw  = (unsigned short*)ws;
    float*          xw   = (float*)(ws + 163840000);
    unsigned short* h3w  = (unsigned short*)(ws + 184320000);
    unsigned short* woT0 = (unsigned short*)(ws + 184320000);
    unsigned short* woT1 = (unsigned short*)(ws + 184320000 + 65536);
    float4*         eap  = (float4*)(ws + 184320000 + 131072);            // NE*16B
    int*            eis  = (int*)(ws + 184320000 + 131072 + 2560000);     // NE*4B
    unsigned short* msgb = (unsigned short*)(ws + 204800000);
    unsigned short* w4T  = (unsigned short*)(ws + 225280000);
    int* ib     = (int*)(ws + 225280000 + 65536);
    int* counts = ib;                        // NN
    int* offs   = ib + 10240;                // NN+1
    int* cursor = ib + 20480;                // NN
    int* elist  = ib + 30720;                // NE
    unsigned short* w1Tp = (unsigned short*)(ws + 226108416);          // 64x32
    unsigned short* w2T  = (unsigned short*)(ws + 226108416 + 4096);   // 64x64
    unsigned short* w3T  = (unsigned short*)(ws + 226108416 + 12288);  // 64x64

    k_wmlp <<<1, 256, 0, stream>>>(W1, W2, W3, w1Tp, w2T, w3T);
    k_up   <<<625, 256, 0, stream>>>(nf, Wu0, Wu1, xw);
    k_mlp  <<<625, 256, 0, stream>>>(ef, w1Tp, w2T, w3T, h3w);
    k_w4t  <<<128, 256, 0, stream>>>(W4, w4T);
    k_zero <<<40, 256, 0, stream>>>(counts, NN);
    k_hist <<<625, 256, 0, stream>>>(ei, counts);
    k_scan <<<1, 1024, 0, stream>>>(counts, offs, cursor);
    k_fill <<<625, 256, 0, stream>>>(ei, cursor, elist);
    k_tpw  <<<625, 256, 0, stream>>>(h3w, w4T, elist, tpw);
    k_wt2  <<<128, 256, 0, stream>>>(Wo0, Wo1, woT0, woT1);   // h3 dead now
    k_gather<<<625, 256, 0, stream>>>(ei, ea, elist, eis, eap);
    k_msg2 <<<NN, 256, 0, stream>>>(xw, tpw, eis, eap, offs, msgb);
    k_out0 <<<157, 256, 0, stream>>>(msgb, woT0, out);
    k_out1 <<<157, 256, 0, stream>>>(msgb, woT1, out);
}

// Round 9
// 385.622 us; speedup vs baseline: 6.8366x; 1.1870x over previous
//
#include <hip/hip_runtime.h>
#include <stdint.h>

#define NN 10000
#define NE 160000

typedef short short8 __attribute__((ext_vector_type(8)));
typedef float f32x4 __attribute__((ext_vector_type(4)));

// ---------- bf16 helpers (internal staging format; I/O is f32) ----------
__device__ __forceinline__ float bf2f(unsigned short u) {
    return __uint_as_float(((uint32_t)u) << 16);
}
__device__ __forceinline__ float bflo(uint32_t u) { return __uint_as_float(u << 16); }
__device__ __forceinline__ float bfhi(uint32_t u) { return __uint_as_float(u & 0xffff0000u); }
__device__ __forceinline__ unsigned short f2bf(float f) {
    uint32_t u = __float_as_uint(f);
    u += 0x7fffu + ((u >> 16) & 1u);   // RNE
    return (unsigned short)(u >> 16);
}
__device__ __forceinline__ uint32_t pack2(float lo, float hi) {
    return (uint32_t)f2bf(lo) | ((uint32_t)f2bf(hi) << 16);
}
__device__ __forceinline__ float silu2(float x) {
    return 1.679177f * x / (1.f + __expf(-x));
}

// ---------------------------------------------------------------------------
// k_wup: transpose up-weights -> [v][u] bf16 with 1/sqrt(128) folded in.
// ---------------------------------------------------------------------------
__global__ __launch_bounds__(256) void k_wup(const float* __restrict__ Wu0,
                                             const float* __restrict__ Wu1,
                                             unsigned short* __restrict__ w0T,
                                             unsigned short* __restrict__ w1T) {
    const float s = 0.08838834764831845f;
    for (int i = threadIdx.x + blockIdx.x * 256; i < 16384; i += 256 * 64) {
        int u = i >> 7, v = i & 127;
        w0T[v * 128 + u] = f2bf(Wu0[i] * s);
        w1T[v * 128 + u] = f2bf(Wu1[i] * s);
    }
}

// ---------------------------------------------------------------------------
// k_prep: nf (f32, [n][512]) -> bf16 MFMA A-planes:
//   x0b[n][u] = nf[n][u];  x1b[m][n][u] = nf[n][128+u*3+m]
// ---------------------------------------------------------------------------
__global__ __launch_bounds__(256) void k_prep(const float* __restrict__ nf,
                                              unsigned short* __restrict__ x0b,
                                              unsigned short* __restrict__ x1b) {
    int idx = blockIdx.x * 256 + threadIdx.x;     // 1,280,000
    int n = idx >> 7, u = idx & 127;
    const float* row = nf + (size_t)n * 512;
    x0b[(size_t)n * 128 + u] = f2bf(row[u]);
    const float* p = row + 128 + u * 3;
    x1b[(size_t)n * 128 + u]                = f2bf(p[0]);
    x1b[1280000 + (size_t)n * 128 + u]      = f2bf(p[1]);
    x1b[2560000 + (size_t)n * 128 + u]      = f2bf(p[2]);
}

// ---------------------------------------------------------------------------
// k_upg (MFMA): y0 = x0 @ W0, y1[m] = x1[m] @ W1 (scales in weights).
// Wave = 16 nodes x 64 cols (2 col-splits per node-tile -> 1250 waves).
// Fragments: A rows [node][k] 16B/lane; B rows [v][k] 16B/lane;
// D row=(lq*4+r)=node, col=lm=v (k_out0-verified convention).
// xw[n]: [y0 (128) | y1 m-major: 128 + m*128 + v]
// ---------------------------------------------------------------------------
__global__ __launch_bounds__(256) void k_upg(const unsigned short* __restrict__ x0b,
                                             const unsigned short* __restrict__ x1b,
                                             const unsigned short* __restrict__ w0T,
                                             const unsigned short* __restrict__ w1T,
                                             float* __restrict__ xw) {
    int wave = threadIdx.x >> 6, lane = threadIdx.x & 63;
    int wid = blockIdx.x * 4 + wave;              // 1250
    if (wid >= 1250) return;
    int tile = wid >> 1, half = wid & 1;
    int n0 = tile * 16;
    int lm = lane & 15, lq = lane >> 4;

    uint4 A0[4], A1[3][4];
    const unsigned short* a0r = x0b + (size_t)(n0 + lm) * 128 + lq * 8;
#pragma unroll
    for (int kf = 0; kf < 4; ++kf) A0[kf] = *(const uint4*)(a0r + kf * 32);
#pragma unroll
    for (int m = 0; m < 3; ++m) {
        const unsigned short* a1r = x1b + 1280000 * (size_t)m + (size_t)(n0 + lm) * 128 + lq * 8;
#pragma unroll
        for (int kf = 0; kf < 4; ++kf) A1[m][kf] = *(const uint4*)(a1r + kf * 32);
    }

    for (int vq = 0; vq < 4; ++vq) {
        int vt = half * 4 + vq;
        const unsigned short* b0r = w0T + (vt * 16 + lm) * 128 + lq * 8;
        const unsigned short* b1r = w1T + (vt * 16 + lm) * 128 + lq * 8;
        f32x4 acc0 = {0.f, 0.f, 0.f, 0.f};
#pragma unroll
        for (int kf = 0; kf < 4; ++kf) {
            short8 b = __builtin_bit_cast(short8, *(const uint4*)(b0r + kf * 32));
            acc0 = __builtin_amdgcn_mfma_f32_16x16x32_bf16(
                __builtin_bit_cast(short8, A0[kf]), b, acc0, 0, 0, 0);
        }
        f32x4 acc1[3];
#pragma unroll
        for (int m = 0; m < 3; ++m) acc1[m] = (f32x4){0.f, 0.f, 0.f, 0.f};
#pragma unroll
        for (int kf = 0; kf < 4; ++kf) {
            short8 b = __builtin_bit_cast(short8, *(const uint4*)(b1r + kf * 32));
#pragma unroll
            for (int m = 0; m < 3; ++m)
                acc1[m] = __builtin_amdgcn_mfma_f32_16x16x32_bf16(
                    __builtin_bit_cast(short8, A1[m][kf]), b, acc1[m], 0, 0, 0);
        }
        int col = vt * 16 + lm;
#pragma unroll
        for (int r = 0; r < 4; ++r) {
            float* o = xw + (size_t)(n0 + lq * 4 + r) * 512;
            o[col] = acc0[r];
            o[128 + col] = acc1[0][r];
            o[256 + col] = acc1[1][r];
            o[384 + col] = acc1[2][r];
        }
    }
}

// ---------------------------------------------------------------------------
// k_wmlp: pre-transpose+scale MLP weights to bf16.
// ---------------------------------------------------------------------------
__global__ __launch_bounds__(256) void k_wmlp(const float* __restrict__ W1,
                                              const float* __restrict__ W2,
                                              const float* __restrict__ W3,
                                              unsigned short* __restrict__ w1Tp,
                                              unsigned short* __restrict__ w2T,
                                              unsigned short* __restrict__ w3T) {
    int t = threadIdx.x;
    for (int i = t; i < 2048; i += 256) {
        int jj = i >> 5, k = i & 31;
        w1Tp[i] = (k < 8) ? f2bf(W1[k * 64 + jj] * 0.3535533905932738f) : 0;
    }
    for (int i = t; i < 4096; i += 256) {
        int jj = i >> 6, k = i & 63;
        w2T[i] = f2bf(W2[k * 64 + jj] * 0.125f);
        w3T[i] = f2bf(W3[k * 64 + jj] * 0.125f);
    }
}

// ---------------------------------------------------------------------------
// K2 (MFMA): edge MLP stages 1-3 -> h3 (NE x 64 bf16). (R7 proven)
// ---------------------------------------------------------------------------
__global__ __launch_bounds__(256) void k_mlp(const float* __restrict__ ef,
                                             const unsigned short* __restrict__ w1Tp,
                                             const unsigned short* __restrict__ w2T,
                                             const unsigned short* __restrict__ w3T,
                                             unsigned short* __restrict__ h3w) {
    __shared__ __align__(16) unsigned short hs_all[4][64 * 72];
    int wave = threadIdx.x >> 6, lane = threadIdx.x & 63;
    int lm = lane & 15, lq = lane >> 4;
    int e0 = blockIdx.x * 256 + wave * 64;
    unsigned short* h = hs_all[wave];

    // stage 1: K=32 (8 real, zero-padded)
    uint4 A1[4];
#pragma unroll
    for (int mt = 0; mt < 4; ++mt)
        A1[mt] = *(const uint4*)(w1Tp + (mt * 16 + lm) * 32 + lq * 8);
#pragma unroll
    for (int nt = 0; nt < 4; ++nt) {
        uint4 b = {0, 0, 0, 0};
        if (lq == 0) {
            const float4* p = (const float4*)(ef + (size_t)(e0 + nt * 16 + lm) * 8);
            float4 x = p[0], y = p[1];
            b.x = pack2(x.x, x.y); b.y = pack2(x.z, x.w);
            b.z = pack2(y.x, y.y); b.w = pack2(y.z, y.w);
        }
        short8 bb = __builtin_bit_cast(short8, b);
        unsigned short* hrow = h + (nt * 16 + lm) * 72;
#pragma unroll
        for (int mt = 0; mt < 4; ++mt) {
            f32x4 acc = {0.f, 0.f, 0.f, 0.f};
            acc = __builtin_amdgcn_mfma_f32_16x16x32_bf16(
                __builtin_bit_cast(short8, A1[mt]), bb, acc, 0, 0, 0);
            uint2 v;
            v.x = pack2(silu2(acc[0]), silu2(acc[1]));
            v.y = pack2(silu2(acc[2]), silu2(acc[3]));
            *(uint2*)(hrow + mt * 16 + lq * 4) = v;
        }
    }

    // stage 2: K=64
    uint4 A2[4][2];
#pragma unroll
    for (int mt = 0; mt < 4; ++mt)
#pragma unroll
        for (int kf = 0; kf < 2; ++kf)
            A2[mt][kf] = *(const uint4*)(w2T + (mt * 16 + lm) * 64 + kf * 32 + lq * 8);
#pragma unroll
    for (int nt = 0; nt < 4; ++nt) {
        unsigned short* hrow = h + (nt * 16 + lm) * 72;
        short8 B0 = __builtin_bit_cast(short8, *(const uint4*)(hrow + lq * 8));
        short8 B1 = __builtin_bit_cast(short8, *(const uint4*)(hrow + 32 + lq * 8));
#pragma unroll
        for (int mt = 0; mt < 4; ++mt) {
            f32x4 acc = {0.f, 0.f, 0.f, 0.f};
            acc = __builtin_amdgcn_mfma_f32_16x16x32_bf16(
                __builtin_bit_cast(short8, A2[mt][0]), B0, acc, 0, 0, 0);
            acc = __builtin_amdgcn_mfma_f32_16x16x32_bf16(
                __builtin_bit_cast(short8, A2[mt][1]), B1, acc, 0, 0, 0);
            uint2 v;
            v.x = pack2(silu2(acc[0]), silu2(acc[1]));
            v.y = pack2(silu2(acc[2]), silu2(acc[3]));
            *(uint2*)(hrow + mt * 16 + lq * 4) = v;
        }
    }

    // stage 3: K=64
    uint4 A3[4][2];
#pragma unroll
    for (int mt = 0; mt < 4; ++mt)
#pragma unroll
        for (int kf = 0; kf < 2; ++kf)
            A3[mt][kf] = *(const uint4*)(w3T + (mt * 16 + lm) * 64 + kf * 32 + lq * 8);
#pragma unroll
    for (int nt = 0; nt < 4; ++nt) {
        unsigned short* hrow = h + (nt * 16 + lm) * 72;
        short8 B0 = __builtin_bit_cast(short8, *(const uint4*)(hrow + lq * 8));
        short8 B1 = __builtin_bit_cast(short8, *(const uint4*)(hrow + 32 + lq * 8));
#pragma unroll
        for (int mt = 0; mt < 4; ++mt) {
            f32x4 acc = {0.f, 0.f, 0.f, 0.f};
            acc = __builtin_amdgcn_mfma_f32_16x16x32_bf16(
                __builtin_bit_cast(short8, A3[mt][0]), B0, acc, 0, 0, 0);
            acc = __builtin_amdgcn_mfma_f32_16x16x32_bf16(
                __builtin_bit_cast(short8, A3[mt][1]), B1, acc, 0, 0, 0);
            uint2 v;
            v.x = pack2(silu2(acc[0]), silu2(acc[1]));
            v.y = pack2(silu2(acc[2]), silu2(acc[3]));
            *(uint2*)(hrow + mt * 16 + lq * 4) = v;
        }
    }

    // flush: coalesced 16B/lane stores
    const unsigned short* hr = h + lane * 72;
    uint4* og = (uint4*)(h3w + (size_t)(e0 + lane) * 64);
#pragma unroll
    for (int q = 0; q < 8; ++q) og[q] = *(const uint4*)(hr + q * 8);
}

// ---------------------------------------------------------------------------
// K3: CSR build by receiver (zero -> histogram -> scan -> fill)
// ---------------------------------------------------------------------------
__global__ void k_zero(int* __restrict__ p, int n) {
    int i = blockIdx.x * 256 + threadIdx.x;
    if (i < n) p[i] = 0;
}
__global__ void k_hist(const int* __restrict__ ei, int* __restrict__ counts) {
    int e = blockIdx.x * 256 + threadIdx.x;
    if (e < NE) atomicAdd(&counts[ei[NE + e]], 1);
}
__global__ __launch_bounds__(1024) void k_scan(const int* __restrict__ counts,
                                               int* __restrict__ offs,
                                               int* __restrict__ cursor) {
    __shared__ int sums[1024];
    int t = threadIdx.x;
    int base = t * 10;
    int s = 0;
    for (int i = 0; i < 10; ++i) {
        int idx = base + i;
        if (idx < NN) s += counts[idx];
    }
    sums[t] = s;
    __syncthreads();
    for (int d = 1; d < 1024; d <<= 1) {
        int v = (t >= d) ? sums[t - d] : 0;
        __syncthreads();
        if (t >= d) sums[t] += v;
        __syncthreads();
    }
    int run = (t == 0) ? 0 : sums[t - 1];
    for (int i = 0; i < 10; ++i) {
        int idx = base + i;
        if (idx < NN) {
            offs[idx] = run;
            cursor[idx] = run;
            run += counts[idx];
        }
    }
    if (t == 0) offs[NN] = NE;
}
__global__ void k_fill(const int* __restrict__ ei, int* __restrict__ cursor,
                       int* __restrict__ elist) {
    int e = blockIdx.x * 256 + threadIdx.x;
    if (e < NE) {
        int slot = atomicAdd(&cursor[ei[NE + e]], 1);
        elist[slot] = e;
    }
}
// k_gather: resolve per-slot sender + edge_attrs
__global__ void k_gather(const int* __restrict__ ei, const float* __restrict__ ea,
                         const int* __restrict__ elist,
                         int* __restrict__ eis, float4* __restrict__ eap) {
    int i = blockIdx.x * 256 + threadIdx.x;
    if (i < NE) {
        int e = elist[i];
        eis[i] = ei[e];
        eap[i] = *(const float4*)(ea + (size_t)e * 4);
    }
}

// ---------------------------------------------------------------------------
// Weight transposes (bf16).
// ---------------------------------------------------------------------------
__global__ void k_w4t(const float* __restrict__ W4, unsigned short* __restrict__ w4T) {
    int idx = blockIdx.x * 256 + threadIdx.x;   // 32768
    int k = idx >> 9, c = idx & 511;
    w4T[c * 64 + k] = f2bf(W4[idx]);
}
__global__ void k_wt2(const float* __restrict__ Wo0, const float* __restrict__ Wo1,
                      unsigned short* __restrict__ woT0, unsigned short* __restrict__ woT1) {
    int idx = blockIdx.x * 256 + threadIdx.x;   // 32768
    int u = idx >> 7, v = idx & 127;
    woT0[v * 256 + u] = f2bf(Wo0[idx]);
    woT1[v * 256 + u] = f2bf(Wo1[idx]);
}

// ---------------------------------------------------------------------------
// k_tpw (PERMUTED): tpw_perm[slot] = (h3[elist[slot]] . W4[:,c]) / 8 via MFMA.
// ---------------------------------------------------------------------------
__global__ __launch_bounds__(256) void k_tpw(const unsigned short* __restrict__ h3w,
                                             const unsigned short* __restrict__ w4T,
                                             const int* __restrict__ elist,
                                             unsigned short* __restrict__ tpw) {
    int wave = threadIdx.x >> 6, lane = threadIdx.x & 63;
    int e0 = blockIdx.x * 256 + wave * 64;
    int lm = lane & 15, lq = lane >> 4;
    uint4 B[4][2];
#pragma unroll
    for (int n = 0; n < 4; ++n) {
        int esrc = elist[e0 + n * 16 + lm];
#pragma unroll
        for (int k = 0; k < 2; ++k)
            B[n][k] = *(const uint4*)(h3w + (size_t)esrc * 64 + k * 32 + lq * 8);
    }
    const unsigned short* aw = w4T + lm * 64 + lq * 8;
    unsigned short* op = tpw + (size_t)e0 * 512;
#pragma unroll 2
    for (int m = 0; m < 32; ++m) {
        f32x4 acc0 = {0.f, 0.f, 0.f, 0.f};
        f32x4 acc1 = {0.f, 0.f, 0.f, 0.f};
        f32x4 acc2 = {0.f, 0.f, 0.f, 0.f};
        f32x4 acc3 = {0.f, 0.f, 0.f, 0.f};
#pragma unroll
        for (int k = 0; k < 2; ++k) {
            uint4 a_raw = *(const uint4*)(aw + m * 1024 + k * 32);
            short8 a = __builtin_bit_cast(short8, a_raw);
            acc0 = __builtin_amdgcn_mfma_f32_16x16x32_bf16(a, __builtin_bit_cast(short8, B[0][k]), acc0, 0, 0, 0);
            acc1 = __builtin_amdgcn_mfma_f32_16x16x32_bf16(a, __builtin_bit_cast(short8, B[1][k]), acc1, 0, 0, 0);
            acc2 = __builtin_amdgcn_mfma_f32_16x16x32_bf16(a, __builtin_bit_cast(short8, B[2][k]), acc2, 0, 0, 0);
            acc3 = __builtin_amdgcn_mfma_f32_16x16x32_bf16(a, __builtin_bit_cast(short8, B[3][k]), acc3, 0, 0, 0);
        }
        int cb = m * 16 + lq * 4;
        uint2 v;
        v.x = pack2(acc0[0] * 0.125f, acc0[1] * 0.125f);
        v.y = pack2(acc0[2] * 0.125f, acc0[3] * 0.125f);
        *(uint2*)(op + (size_t)(0 * 16 + lm) * 512 + cb) = v;
        v.x = pack2(acc1[0] * 0.125f, acc1[1] * 0.125f);
        v.y = pack2(acc1[2] * 0.125f, acc1[3] * 0.125f);
        *(uint2*)(op + (size_t)(1 * 16 + lm) * 512 + cb) = v;
        v.x = pack2(acc2[0] * 0.125f, acc2[1] * 0.125f);
        v.y = pack2(acc2[2] * 0.125f, acc2[3] * 0.125f);
        *(uint2*)(op + (size_t)(2 * 16 + lm) * 512 + cb) = v;
        v.x = pack2(acc3[0] * 0.125f, acc3[1] * 0.125f);
        v.y = pack2(acc3[2] * 0.125f, acc3[3] * 0.125f);
        *(uint2*)(op + (size_t)(3 * 16 + lm) * 512 + cb) = v;
    }
}

// ---------------------------------------------------------------------------
// k_msg2: tensor product + reduce. tpw/eis/eap sequential per block range.
// ---------------------------------------------------------------------------
__global__ __launch_bounds__(256) void k_msg2(const float* __restrict__ xw,
                                              const unsigned short* __restrict__ tpw,
                                              const int* __restrict__ eis,
                                              const float4* __restrict__ eap,
                                              const int* __restrict__ offs,
                                              unsigned short* __restrict__ msgb) {
    int n = blockIdx.x, t = threadIdx.x;
    int j = t >> 6, c0 = (t & 63) * 2;
    int beg = offs[n], end = offs[n + 1];
    float a0 = 0.f, a1 = 0.f, a2 = 0.f, a3 = 0.f, a4 = 0.f, a5 = 0.f;
    for (int i = beg; i < end; ++i) {
        int snd = eis[i];
        float4 eav = eap[i];
        float y0 = eav.x, y1x = eav.y, y1y = eav.z, y1z = eav.w;
        uint32_t wp = ((const uint32_t*)tpw)[(size_t)i * 256 + t];
        float wa = bflo(wp), wb = bfhi(wp);
        const float* xr = xw + (size_t)snd * 512;
        if (j == 0) {
            a0 += wa * xr[c0] * y0;
            a1 += wb * xr[c0 + 1] * y0;
        } else if (j == 1) {
            float ta = wa * xr[c0], tb = wb * xr[c0 + 1];
            a0 += ta * y1x; a1 += ta * y1y; a2 += ta * y1z;
            a3 += tb * y1x; a4 += tb * y1y; a5 += tb * y1z;
        } else if (j == 2) {
            float f0 = wa * y0, f1 = wb * y0;
            a0 += f0 * xr[128 + c0]; a1 += f0 * xr[256 + c0]; a2 += f0 * xr[384 + c0];
            a3 += f1 * xr[128 + c0 + 1]; a4 += f1 * xr[256 + c0 + 1]; a5 += f1 * xr[384 + c0 + 1];
        } else {
            float dta = xr[128 + c0] * y1x + xr[256 + c0] * y1y + xr[384 + c0] * y1z;
            float dtb = xr[128 + c0 + 1] * y1x + xr[256 + c0 + 1] * y1y + xr[384 + c0 + 1] * y1z;
            a0 += wa * dta * 0.5773502691896258f;
            a1 += wb * dtb * 0.5773502691896258f;
        }
    }
    unsigned short* mr = msgb + (size_t)n * 1024;
    if (j == 0) {
        *(uint32_t*)(mr + c0) = pack2(a0, a1);
    } else if (j == 1) {
        *(uint32_t*)(mr + 256 + c0)       = pack2(a0, a3);
        *(uint32_t*)(mr + 256 + 256 + c0) = pack2(a1, a4);
        *(uint32_t*)(mr + 256 + 512 + c0) = pack2(a2, a5);
    } else if (j == 2) {
        *(uint32_t*)(mr + 256 + 128 + c0)       = pack2(a0, a3);
        *(uint32_t*)(mr + 256 + 256 + 128 + c0) = pack2(a1, a4);
        *(uint32_t*)(mr + 256 + 512 + 128 + c0) = pack2(a2, a5);
    } else {
        *(uint32_t*)(mr + 128 + c0) = pack2(a0, a1);
    }
}

// ---------------------------------------------------------------------------
// k_out0 (MFMA): o0 = msg0 @ Wo0 /16/10.  M=10000 nodes, N=128, K=256.
// ---------------------------------------------------------------------------
__global__ __launch_bounds__(256) void k_out0(const unsigned short* __restrict__ msgb,
                                              const unsigned short* __restrict__ woT,
                                              float* __restrict__ out) {
    int wave = threadIdx.x >> 6, lane = threadIdx.x & 63;
    int wid = blockIdx.x * 4 + wave;
    if (wid >= NN / 16) return;
    int n0 = wid * 16;
    int lm = lane & 15, lq = lane >> 4;
    uint4 A[8];
    const unsigned short* ar = msgb + (size_t)(n0 + lm) * 1024 + lq * 8;
#pragma unroll
    for (int kf = 0; kf < 8; ++kf) A[kf] = *(const uint4*)(ar + kf * 32);
    const unsigned short* br = woT + lm * 256 + lq * 8;
    float* ob = out + (size_t)n0 * 512;
    for (int vt = 0; vt < 8; ++vt) {
        f32x4 acc = {0.f, 0.f, 0.f, 0.f};
#pragma unroll
        for (int kf = 0; kf < 8; ++kf) {
            uint4 b = *(const uint4*)(br + vt * 16 * 256 + kf * 32);
            acc = __builtin_amdgcn_mfma_f32_16x16x32_bf16(
                __builtin_bit_cast(short8, A[kf]), __builtin_bit_cast(short8, b), acc, 0, 0, 0);
        }
#pragma unroll
        for (int r = 0; r < 4; ++r)
            ob[(size_t)(lq * 4 + r) * 512 + vt * 16 + lm] = acc[r] * 0.00625f;
    }
}

// ---------------------------------------------------------------------------
// k_out1 (MFMA): 3 GEMMs sharing B = woT1 -> out[n][128 + v*3 + m].
// ---------------------------------------------------------------------------
__global__ __launch_bounds__(256) void k_out1(const unsigned short* __restrict__ msgb,
                                              const unsigned short* __restrict__ woT,
                                              float* __restrict__ out) {
    int wave = threadIdx.x >> 6, lane = threadIdx.x & 63;
    int wid = blockIdx.x * 4 + wave;
    if (wid >= NN / 16) return;
    int n0 = wid * 16;
    int lm = lane & 15, lq = lane >> 4;
    uint4 A[3][8];
    const unsigned short* ar = msgb + (size_t)(n0 + lm) * 1024 + 256 + lq * 8;
#pragma unroll
    for (int m = 0; m < 3; ++m)
#pragma unroll
        for (int kf = 0; kf < 8; ++kf)
            A[m][kf] = *(const uint4*)(ar + m * 256 + kf * 32);
    const unsigned short* br = woT + lm * 256 + lq * 8;
    float* ob = out + (size_t)n0 * 512 + 128;
    for (int vt = 0; vt < 8; ++vt) {
        f32x4 acc[3];
#pragma unroll
        for (int m = 0; m < 3; ++m) acc[m] = (f32x4){0.f, 0.f, 0.f, 0.f};
#pragma unroll
        for (int kf = 0; kf < 8; ++kf) {
            uint4 braw = *(const uint4*)(br + vt * 16 * 256 + kf * 32);
            short8 b = __builtin_bit_cast(short8, braw);
#pragma unroll
            for (int m = 0; m < 3; ++m)
                acc[m] = __builtin_amdgcn_mfma_f32_16x16x32_bf16(
                    __builtin_bit_cast(short8, A[m][kf]), b, acc[m], 0, 0, 0);
        }
        int vb = (vt * 16 + lm) * 3;
#pragma unroll
        for (int r = 0; r < 4; ++r) {
            float* o = ob + (size_t)(lq * 4 + r) * 512 + vb;
            o[0] = acc[0][r] * 0.00625f;
            o[1] = acc[1][r] * 0.00625f;
            o[2] = acc[2][r] * 0.00625f;
        }
    }
}

// ---------------------------------------------------------------------------
extern "C" void kernel_launch(void* const* d_in, const int* in_sizes, int n_in,
                              void* d_out, int out_size, void* d_ws, size_t ws_size,
                              hipStream_t stream) {
    const float* nf  = (const float*)d_in[0];
    const float* ea  = (const float*)d_in[1];
    const float* ef  = (const float*)d_in[2];
    const int*   ei  = (const int*)d_in[3];
    const float* Wu0 = (const float*)d_in[4];
    const float* Wu1 = (const float*)d_in[5];
    const float* W1  = (const float*)d_in[6];
    const float* W2  = (const float*)d_in[7];
    const float* W3  = (const float*)d_in[8];
    const float* W4  = (const float*)d_in[9];
    const float* Wo0 = (const float*)d_in[10];
    const float* Wo1 = (const float*)d_in[11];
    float* out = (float*)d_out;
    char* ws = (char*)d_ws;

    // Layout (ws >= 226.2 MB proven):
    //   tpw [0, 163.84M)  xw [163.84M, 184.32M)  h3 [184.32M, 204.8M)
    //   msg [204.8M, 225.28M)  w4T [225.28M, +64K)  CSR ints  small weights.
    //   x0b/x1b alias tpw head (dead before k_tpw);
    //   woT0/woT1 + eis/eap alias h3 (dead after k_tpw).
    unsigned short* tpw  = (unsigned short*)ws;
    unsigned short* x0b  = (unsigned short*)ws;                 // 2.56 MB
    unsigned short* x1b  = (unsigned short*)(ws + 2560000);     // 7.68 MB
    float*          xw   = (float*)(ws + 163840000);
    unsigned short* h3w  = (unsigned short*)(ws + 184320000);
    unsigned short* woT0 = (unsigned short*)(ws + 184320000);
    unsigned short* woT1 = (unsigned short*)(ws + 184320000 + 65536);
    float4*         eap  = (float4*)(ws + 184320000 + 131072);            // NE*16B
    int*            eis  = (int*)(ws + 184320000 + 131072 + 2560000);     // NE*4B
    unsigned short* msgb = (unsigned short*)(ws + 204800000);
    unsigned short* w4T  = (unsigned short*)(ws + 225280000);
    int* ib     = (int*)(ws + 225280000 + 65536);
    int* counts = ib;                        // NN
    int* offs   = ib + 10240;                // NN+1
    int* cursor = ib + 20480;                // NN
    int* elist  = ib + 30720;                // NE
    unsigned short* w1Tp = (unsigned short*)(ws + 226108416);          // 64x32
    unsigned short* w2T  = (unsigned short*)(ws + 226108416 + 4096);   // 64x64
    unsigned short* w3T  = (unsigned short*)(ws + 226108416 + 12288);  // 64x64
    unsigned short* w0T  = (unsigned short*)(ws + 226128896);          // 128x128 (32KB)
    unsigned short* w1T  = (unsigned short*)(ws + 226161664);          // 128x128 (32KB)

    k_wmlp <<<1, 256, 0, stream>>>(W1, W2, W3, w1Tp, w2T, w3T);
    k_wup  <<<64, 256, 0, stream>>>(Wu0, Wu1, w0T, w1T);
    k_prep <<<5000, 256, 0, stream>>>(nf, x0b, x1b);
    k_upg  <<<313, 256, 0, stream>>>(x0b, x1b, w0T, w1T, xw);
    k_mlp  <<<625, 256, 0, stream>>>(ef, w1Tp, w2T, w3T, h3w);
    k_w4t  <<<128, 256, 0, stream>>>(W4, w4T);
    k_zero <<<40, 256, 0, stream>>>(counts, NN);
    k_hist <<<625, 256, 0, stream>>>(ei, counts);
    k_scan <<<1, 1024, 0, stream>>>(counts, offs, cursor);
    k_fill <<<625, 256, 0, stream>>>(ei, cursor, elist);
    k_tpw  <<<625, 256, 0, stream>>>(h3w, w4T, elist, tpw);
    k_wt2  <<<128, 256, 0, stream>>>(Wo0, Wo1, woT0, woT1);   // h3 dead now
    k_gather<<<625, 256, 0, stream>>>(ei, ea, elist, eis, eap);
    k_msg2 <<<NN, 256, 0, stream>>>(xw, tpw, eis, eap, offs, msgb);
    k_out0 <<<157, 256, 0, stream>>>(msgb, woT0, out);
    k_out1 <<<157, 256, 0, stream>>>(msgb, woT1, out);
}